// Round 2
// baseline (783.739 us; speedup 1.0000x reference)
//
#include <hip/hip_runtime.h>
#include <hip/hip_bf16.h>
#include <math.h>

// ---- static config (matches reference) ----
#define B_      8
#define DIMC    512
#define SEQ_    784
#define HEADS_  8
#define DH_     64
#define NTOK    (B_*SEQ_)      // 6272
#define QLD     1560           // q(512) | k(512) | v(512) | gates(24)
#define WIN_    196
#define CBS_    392
#define CST_    196
#define NC_     3
#define EPSF    1e-5f
#define FF_     2048
#define TQ_     28             // queries per block (28*28 = 784)

typedef __hip_bfloat16 bf16_t;
typedef __attribute__((ext_vector_type(8))) short bf16x8;
typedef __attribute__((ext_vector_type(4))) float floatx4;
typedef __attribute__((ext_vector_type(4))) unsigned int uintx4;
typedef __attribute__((ext_vector_type(2))) unsigned int uintx2;

// ---------------- helpers ----------------
__device__ __forceinline__ float wsum(float x){
#pragma unroll
  for (int o = 32; o; o >>= 1) x += __shfl_xor(x, o, 64);
  return x;
}
__device__ __forceinline__ float geluf(float x){
  return 0.5f * x * (1.0f + erff(x * 0.70710678118654752f));
}
__device__ __forceinline__ float sigmoidf_(float x){
  return 1.0f / (1.0f + __expf(-x));
}
// async global->LDS 16B (dest = wave-uniform base + lane*16; completion via vmcnt)
__device__ __forceinline__ void gload16(const bf16_t* g, bf16_t* l){
  __builtin_amdgcn_global_load_lds(
      (const __attribute__((address_space(1))) void*)g,
      (__attribute__((address_space(3))) void*)l, 16, 0, 0);
}

// ---------------- init: x[b,c,h,w] (f32) -> X[b,p,c] (f32) + pos ----------------
__global__ __launch_bounds__(256) void k_init(const float* __restrict__ xin,
                                              const float* __restrict__ pos,
                                              float* __restrict__ X){
  int idx = blockIdx.x * 256 + threadIdx.x;       // over NTOK*512 (exact)
  int c = idx & 511;
  int t = idx >> 9;          // b*784 + p
  int p = t % SEQ_;
  int b = t / SEQ_;
  float v = xin[((long)(b * DIMC + c)) * SEQ_ + p];
  X[idx] = v + pos[p];
}

// ---------------- final: X[b,p,c] -> out[b,c,h,w] f32 ----------------
__global__ __launch_bounds__(256) void k_final(const float* __restrict__ X,
                                               float* __restrict__ out){
  int idx = blockIdx.x * 256 + threadIdx.x;       // over B*DIMC*SEQ (exact)
  int p = idx % SEQ_;
  int t = idx / SEQ_;        // b*512 + c
  int c = t & 511;
  int b = t >> 9;
  out[idx] = X[((long)(b * SEQ_ + p)) * DIMC + c];
}

// ---------------- weight conversion: WQKVG [l][n 0..1559][k 0..511] bf16 (transposed) ----
__global__ __launch_bounds__(256) void k_wconv1(const float* __restrict__ Wq,
                                                const float* __restrict__ Wk,
                                                const float* __restrict__ Wv,
                                                const float* __restrict__ Wg,
                                                bf16_t* __restrict__ Wb){
  int idx = blockIdx.x * 256 + threadIdx.x;   // over 2*1560*512 (6240 blocks, exact)
  int k = idx & 511;
  int t = idx >> 9;
  int n = t % QLD;
  int l = t / QLD;
  float v;
  if (n < 1536){
    int which = n >> 9;
    int nn = n & 511;
    const float* W = (which == 0) ? Wq : ((which == 1) ? Wk : Wv);
    v = W[((long)(l * 512 + k)) * 512 + nn];
  } else {
    v = Wg[((long)(l * 512 + k)) * 24 + (n - 1536)];
  }
  Wb[idx] = __float2bfloat16(v);
}

// ---------------- WO transpose: Wb[l][n][k] = Wo[l][k][n] ----------------
__global__ __launch_bounds__(256) void k_wconv2(const float* __restrict__ Wo,
                                                bf16_t* __restrict__ Wb){
  int idx = blockIdx.x * 256 + threadIdx.x;   // over 2*512*512 (2048 blocks)
  int k = idx & 511;
  int t = idx >> 9;
  int n = t & 511;
  int l = t >> 9;
  Wb[idx] = __float2bfloat16(Wo[((long)(l * 512 + k)) * 512 + n]);
}

// ---------------- plain f32 -> bf16 cast ----------------
__global__ __launch_bounds__(256) void k_cast(const float* __restrict__ src,
                                              bf16_t* __restrict__ dst){
  int idx = blockIdx.x * 256 + threadIdx.x;
  dst[idx] = __float2bfloat16(src[idx]);
}

// ---------------- 16B-granular zero fill ----------------
__global__ __launch_bounds__(256) void k_zero(uintx4* __restrict__ p){
  p[blockIdx.x * 256 + threadIdx.x] = (uintx4){0u, 0u, 0u, 0u};
}

// ---------------- RMSNorm: f32 in -> bf16 out ----------------
__global__ __launch_bounds__(256) void k_rms(const float* __restrict__ X,
                                             const float* __restrict__ g,
                                             bf16_t* __restrict__ XR){
  int tok = blockIdx.x;
  int tid = threadIdx.x;
  const float* xr = X + (long)tok * DIMC;
  float v0 = xr[tid], v1 = xr[tid + 256];
  float ss = v0 * v0 + v1 * v1;
  ss = wsum(ss);
  __shared__ float red[4];
  if ((tid & 63) == 0) red[tid >> 6] = ss;
  __syncthreads();
  float tot = red[0] + red[1] + red[2] + red[3];
  float r = rsqrtf(tot * (1.0f / DIMC) + EPSF);
  XR[(long)tok * DIMC + tid]       = __float2bfloat16(v0 * r * g[tid]);
  XR[(long)tok * DIMC + tid + 256] = __float2bfloat16(v1 * r * g[tid + 256]);
}

// ---------------- LayerNorm: f32 in -> bf16 out ----------------
__global__ __launch_bounds__(256) void k_ln(const float* __restrict__ X,
                                            const float* __restrict__ g,
                                            const float* __restrict__ bb,
                                            bf16_t* __restrict__ XN){
  int tok = blockIdx.x;
  int tid = threadIdx.x;
  const float* xr = X + (long)tok * DIMC;
  float v0 = xr[tid], v1 = xr[tid + 256];
  float s = v0 + v1;
  float q = v0 * v0 + v1 * v1;
  s = wsum(s); q = wsum(q);
  __shared__ float r1[4], r2[4];
  if ((tid & 63) == 0){ r1[tid >> 6] = s; r2[tid >> 6] = q; }
  __syncthreads();
  float ts = r1[0] + r1[1] + r1[2] + r1[3];
  float tq = r2[0] + r2[1] + r2[2] + r2[3];
  float mean = ts * (1.0f / DIMC);
  float var  = tq * (1.0f / DIMC) - mean * mean;
  float rinv = rsqrtf(var + EPSF);
  XN[(long)tok * DIMC + tid]       = __float2bfloat16((v0 - mean) * rinv * g[tid]       + bb[tid]);
  XN[(long)tok * DIMC + tid + 256] = __float2bfloat16((v1 - mean) * rinv * g[tid + 256] + bb[tid + 256]);
}

// ---------------- bf16 MFMA GEMM v2: m97 structure ---------------------------------
// 128x128 tile, BK=32, 4 waves x (64x64 wave-tile, 4x4 16x16x32 frags),
// global_load_lds width-16 staging, double-buffered LDS, 1 barrier/chunk with
// prefetch issued before the MFMAs (loads drain at the barrier after compute).
// Grid = mtiles*ntiles exactly, bijective XCD swizzle (m204). B rows clamped for
// ragged N (global side of global_load_lds is per-lane); stores guarded.
// VTo != nullptr (QKVG GEMM only): also write V columns (ncol in [1024,1536))
// transposed to VTo[b*512 + d][tok] (bf16, row width 800; cols 784..799 pre-zeroed).
template<int OUTBF, int ACT>
__global__ __launch_bounds__(256) void k_mgemm(const bf16_t* __restrict__ A,
                                               const bf16_t* __restrict__ Bm,
                                               float* Cf,
                                               bf16_t* Cb,
                                               const float* __restrict__ bias,
                                               const float* res,
                                               int M, int N, int K, int ldc, int ccol,
                                               bf16_t* VTo){
  // bijective XCD swizzle: consecutive wg on one XCD -> same B n-panel (L2 reuse)
  int nwg = gridDim.x;
  int orig = blockIdx.x;
  int qd = nwg >> 3, rm = nwg & 7;
  int xcd = orig & 7, sidx = orig >> 3;
  int wg = (xcd < rm ? xcd * (qd + 1) : rm * (qd + 1) + (xcd - rm) * qd) + sidx;
  int mtiles = M >> 7;                 // M multiple of 128 in all uses
  int mt = wg % mtiles, nt = wg / mtiles;
  int bm = mt * 128, bn = nt * 128;

  __shared__ bf16_t As[2][128][32];    // 8 KB each buf
  __shared__ bf16_t Bs[2][128][32];

  int tid = threadIdx.x;
  int w = tid >> 6, lane = tid & 63;
  int quad = lane >> 4, l16 = lane & 15;
  int wm = (w & 1) * 64, wn = (w >> 1) * 64;

  // staging geometry: wave w covers rows w*32..w*32+31, two instrs (i=0:+0, i=1:+16)
  int srow = w * 32 + (lane >> 2);
  int scol = (lane & 3) * 8;
  const bf16_t* agp0 = A + (long)(bm + srow) * K + scol;
  const bf16_t* agp1 = A + (long)(bm + srow + 16) * K + scol;
  int br0 = bn + srow;      if (br0 >= N) br0 = N - 1;
  int br1 = bn + srow + 16; if (br1 >= N) br1 = N - 1;
  const bf16_t* bgp0 = Bm + (long)br0 * K + scol;
  const bf16_t* bgp1 = Bm + (long)br1 * K + scol;

  floatx4 acc[4][4];
#pragma unroll
  for (int i = 0; i < 4; i++)
#pragma unroll
    for (int jj = 0; jj < 4; jj++) acc[i][jj] = (floatx4)(0.0f);

  int nch = K >> 5;
  // prologue: stage chunk 0 into buf 0
  gload16(agp0, &As[0][srow][scol]);
  gload16(agp1, &As[0][srow + 16][scol]);
  gload16(bgp0, &Bs[0][srow][scol]);
  gload16(bgp1, &Bs[0][srow + 16][scol]);
  __syncthreads();

  int cur = 0;
  for (int ch = 0; ch < nch; ch++){
    if (ch + 1 < nch){
      int ko = (ch + 1) * 32;
      gload16(agp0 + ko, &As[cur ^ 1][srow][scol]);
      gload16(agp1 + ko, &As[cur ^ 1][srow + 16][scol]);
      gload16(bgp0 + ko, &Bs[cur ^ 1][srow][scol]);
      gload16(bgp1 + ko, &Bs[cur ^ 1][srow + 16][scol]);
    }
    bf16x8 af[4], bfr[4];
#pragma unroll
    for (int f = 0; f < 4; f++){
      af[f]  = *(bf16x8*)&As[cur][wm + f * 16 + l16][quad * 8];
      bfr[f] = *(bf16x8*)&Bs[cur][wn + f * 16 + l16][quad * 8];
    }
#pragma unroll
    for (int i = 0; i < 4; i++)
#pragma unroll
      for (int jj = 0; jj < 4; jj++)
        acc[i][jj] = __builtin_amdgcn_mfma_f32_16x16x32_bf16(af[i], bfr[jj], acc[i][jj], 0, 0, 0);
    __syncthreads();   // drains prefetch (vmcnt) + orders reads before next writes
    cur ^= 1;
  }

#pragma unroll
  for (int tm = 0; tm < 4; tm++){
#pragma unroll
    for (int tn = 0; tn < 4; tn++){
      int ncol = bn + wn + tn * 16 + l16;
      if (ncol >= N) continue;
#pragma unroll
      for (int reg = 0; reg < 4; reg++){
        long mrow = bm + wm + tm * 16 + quad * 4 + reg;
        float v = acc[tm][tn][reg];
        if (bias) v += bias[ncol];
        if (ACT == 1) v = geluf(v);
        long off = mrow * (long)ldc + ccol + ncol;
        if (res) v += res[off];
        if (OUTBF){
          Cb[off] = __float2bfloat16(v);
          if (VTo && ncol >= 1024 && ncol < 1536){
            int bb2 = (int)(mrow / SEQ_);
            int tok = (int)(mrow - (long)bb2 * SEQ_);
            VTo[((long)(bb2 * 512 + (ncol - 1024))) * 800 + tok] = __float2bfloat16(v);
          }
        }
        else       Cf[off] = v;
      }
    }
  }
}

// ---------------- compressed-block mean pooling, vectorized + coalesced -------------
__global__ __launch_bounds__(512) void k_cpool(const bf16_t* __restrict__ qkvg,
                                               float* __restrict__ ck,
                                               float* __restrict__ cv){
  int bj = blockIdx.x;
  int j = bj % NC_;
  int b = bj / NC_;
  int tid = threadIdx.x;
  int seg = tid & 127;
  int rg  = tid >> 7;
  __shared__ float part[4][1024];
  const bf16_t* base = qkvg + ((long)b * SEQ_ + (long)j * CST_) * QLD + 512;
  float acc[8] = {0.f,0.f,0.f,0.f,0.f,0.f,0.f,0.f};
  for (int r = rg; r < CBS_; r += 4){
    uintx4 v = *(const uintx4*)(base + (long)r * QLD + seg * 8);
    bf16_t tmp[8]; *(uintx4*)tmp = v;
#pragma unroll
    for (int q = 0; q < 8; q++) acc[q] += __bfloat162float(tmp[q]);
  }
#pragma unroll
  for (int q = 0; q < 8; q++) part[rg][seg * 8 + q] = acc[q];
  __syncthreads();
  for (int c = tid; c < 1024; c += 512){
    float s = (part[0][c] + part[1][c]) + (part[2][c] + part[3][c]);
    s *= (1.0f / CBS_);
    if (c < 512) ck[bj * DIMC + c] = s;
    else         cv[bj * DIMC + (c - 512)] = s;
  }
}

// ---------------- fused NSA attention v6 (unchanged this round) ---------------------
__global__ __launch_bounds__(256) void k_attn(const bf16_t* __restrict__ qkvg,
                                              const float* __restrict__ ck,
                                              const float* __restrict__ cv,
                                              const bf16_t* __restrict__ vtg,
                                              bf16_t* __restrict__ oattn){
  int tid = threadIdx.x;
  int w = tid >> 6, lane = tid & 63;
  int quad = lane >> 4, l16 = lane & 15;
  int id = blockIdx.x;
  int xcd = id & 7;
  int j = id >> 3;               // 0..223
  int bh = xcd * 8 + (j / 28);   // all 28 tiles of a bh on one XCD
  int i0 = (j % 28) * TQ_;
  int h = bh & 7, b = bh >> 3;
  const float scale = 0.125f;

  __shared__ __align__(16) char smem[77040];
  bf16_t (*Qs)[72]    = (bf16_t(*)[72])(smem);             // 4608 B (rows 28-31 zero)
  bf16_t (*Ks0)[72]   = (bf16_t(*)[72])(smem + 4608);      // 9216 B (dbuf 0, 64 keys)
  bf16_t (*Ks1)[72]   = (bf16_t(*)[72])(smem + 13824);     // 9216 B (dbuf 1)
  bf16_t (*sbuf)[808] = (bf16_t(*)[808])(smem + 23040);    // 45248 B
  float  (*outc_s)[64]= (float(*)[64])(smem + 68288);      // 7168 B (absorbs overreads)
  int*   sel_s = (int*)(smem + 75456);                     // 112 B
  float* cw_s  = (float*)(smem + 75568);                   // 112 B
  float* cs_s  = (float*)(smem + 75680);                   // 112 B
  float* g1_s  = (float*)(smem + 75792);                   // 112 B
  float* g2_s  = (float*)(smem + 75904);                   // 112 B
  float (*red_s)[4][16] = (float(*)[4][16])(smem + 76016); // 1024 B

  const long rowBase = (long)b * SEQ_ * QLD + h * 64;     // + token*QLD + {0,512,1024}

  // ---- Phase A: stage Q tile (28 rows) + zero rows 28-31 ----
  if (tid < 224){
    int q = tid >> 3, seg = tid & 7;
    uintx4 qv = *(const uintx4*)(qkvg + rowBase + (long)(i0 + q) * QLD + seg * 8);
    *(uintx4*)&Qs[q][seg * 8] = qv;
  } else {
    int u = tid - 224;
    int r = 28 + (u >> 3), seg = u & 7;
    *(uintx4*)&Qs[r][seg * 8] = (uintx4){0u, 0u, 0u, 0u};
  }
  __syncthreads();

  // ---- prefetch K chunk 0 (latency hidden under Phase B) ----
  int r0i = tid >> 3, s0i = tid & 7;
  int r1i = 32 + r0i;
  uintx4 kreg0 = *(const uintx4*)(qkvg + rowBase + (long)r0i * QLD + 512 + s0i * 8);
  uintx4 kreg1 = *(const uintx4*)(qkvg + rowBase + (long)r1i * QLD + 512 + s0i * 8);

  // ---- Phase B: compressed branch + gates + top-1 selection ----
  {
    const float* CKp = ck + (long)b * NC_ * DIMC + h * 64 + lane;
    const float* CVp = cv + (long)b * NC_ * DIMC + h * 64 + lane;
    float k0 = CKp[0], k1 = CKp[512], k2 = CKp[1024];
    float v0 = CVp[0], v1 = CVp[512], v2 = CVp[1024];
#pragma unroll
    for (int qp = 0; qp < 7; qp++){
      int qg = w * 7 + qp;
      float qd = __bfloat162float(Qs[qg][lane]);
      float s0 = wsum(qd * k0) * scale;
      float s1 = wsum(qd * k1) * scale;
      float s2 = wsum(qd * k2) * scale;
      float m3 = fmaxf(s0, fmaxf(s1, s2));
      float e0 = __expf(s0 - m3), e1 = __expf(s1 - m3), e2 = __expf(s2 - m3);
      float inv = 1.0f / (e0 + e1 + e2);
      const bf16_t* grow = qkvg + (long)(b * SEQ_ + i0 + qg) * QLD + 1536 + h * 3;
      float g0 = sigmoidf_(__bfloat162float(grow[0]));
      float g1v = sigmoidf_(__bfloat162float(grow[1]));
      float g2v = sigmoidf_(__bfloat162float(grow[2]));
      outc_s[qg][lane] = g0 * (e0 * v0 + e1 * v1 + e2 * v2) * inv;
      int selv = (s2 > s0) ? 1 : 0;   // imp1>imp0 <=> p2>p0 <=> s2>s0
      if (lane == 0){ sel_s[qg] = selv; g1_s[qg] = g1v; g2_s[qg] = g2v; }
    }
  }

  // hoist Q B-fragments (chunk-invariant)
  bf16x8 a00 = *(bf16x8*)&Qs[l16][quad * 8];
  bf16x8 a01 = *(bf16x8*)&Qs[l16][32 + quad * 8];
  bf16x8 a10 = *(bf16x8*)&Qs[16 + l16][quad * 8];
  bf16x8 a11 = *(bf16x8*)&Qs[16 + l16][32 + quad * 8];

  __syncthreads();   // sel_s/g1_s/g2_s/outc_s visible to all waves

  // ---- Phase C: S^T = K.Q^T via MFMA (13 chunks of 64 keys, dbuf + reg prefetch) --
  int sel0i = sel_s[l16];
  int sel1i = (l16 < 12) ? sel_s[16 + l16] : 0;
  bool sv0 = (sel0i != 0), sv1 = (sel1i != 0);
  int iq0 = i0 + l16, iq1 = i0 + 16 + l16;
  float sw0 = 0.f, ss0 = 0.f, sw1 = 0.f, ss1 = 0.f;

  for (int ch = 0; ch < 13; ch++){
    bf16_t (*Kb)[72] = (ch & 1) ? Ks1 : Ks0;
    *(uintx4*)&Kb[r0i][s0i * 8] = kreg0;
    *(uintx4*)&Kb[r1i][s0i * 8] = kreg1;
    if (ch + 1 < 13){
      int c0n = (ch + 1) * 64;
      int t0 = c0n + r0i; if (t0 > 783) t0 = 783;
      int t1 = c0n + r1i; if (t1 > 783) t1 = 783;
      kreg0 = *(const uintx4*)(qkvg + rowBase + (long)t0 * QLD + 512 + s0i * 8);
      kreg1 = *(const uintx4*)(qkvg + rowBase + (long)t1 * QLD + 512 + s0i * 8);
    }
    __syncthreads();
    bf16x8 k0 = *(bf16x8*)&Kb[w * 16 + l16][quad * 8];
    bf16x8 k1 = *(bf16x8*)&Kb[w * 16 + l16][32 + quad * 8];
    floatx4 d0 = (floatx4)(0.0f), d1 = (floatx4)(0.0f);
    d0 = __builtin_amdgcn_mfma_f32_16x16x32_bf16(k0, a00, d0, 0, 0, 0);
    d0 = __builtin_amdgcn_mfma_f32_16x16x32_bf16(k1, a01, d0, 0, 0, 0);
    d1 = __builtin_amdgcn_mfma_f32_16x16x32_bf16(k0, a10, d1, 0, 0, 0);
    d1 = __builtin_amdgcn_mfma_f32_16x16x32_bf16(k1, a11, d1, 0, 0, 0);
    int kb = ch * 64 + w * 16 + quad * 4;
    union { bf16_t hh[4]; uintx2 v; } p0, p1;
#pragma unroll
    for (int r = 0; r < 4; r++){
      int key = kb + r;
      float ex0 = __expf(d0[r] * scale);
      float ex1 = __expf(d1[r] * scale);
      bool valid = key < 784;
      if (valid && key >= iq0 - 195 && key <= iq0 + 195) sw0 += ex0;
      if (valid && ((key >= 392) == sv0))                ss0 += ex0;
      if (valid && key >= iq1 - 195 && key <= iq1 + 195) sw1 += ex1;
      if (valid && ((key >= 392) == sv1))                ss1 += ex1;
      p0.hh[r] = __float2bfloat16(ex0);
      p1.hh[r] = __float2bfloat16(ex1);
    }
    if (kb < 784){
      *(uintx2*)&sbuf[l16][kb] = p0.v;
      if (l16 < 12) *(uintx2*)&sbuf[16 + l16][kb] = p1.v;
    }
  }

  // ---- combine row sums: quads via shfl, waves via 1KB LDS ----
  sw0 += __shfl_xor(sw0, 16, 64); sw0 += __shfl_xor(sw0, 32, 64);
  ss0 += __shfl_xor(ss0, 16, 64); ss0 += __shfl_xor(ss0, 32, 64);
  sw1 += __shfl_xor(sw1, 16, 64); sw1 += __shfl_xor(sw1, 32, 64);
  ss1 += __shfl_xor(ss1, 16, 64); ss1 += __shfl_xor(ss1, 32, 64);
  if (quad == 0){
    red_s[w][0][l16] = sw0; red_s[w][1][l16] = ss0;
    red_s[w][2][l16] = sw1; red_s[w][3][l16] = ss1;
  }
  __syncthreads();
  if (tid < 28){
    int q = tid, t = q >> 4, l = q & 15;
    float sw = 0.f, ss = 0.f;
#pragma unroll
    for (int wv = 0; wv < 4; wv++){ sw += red_s[wv][2 * t][l]; ss += red_s[wv][2 * t + 1][l]; }
    cw_s[q] = g2_s[q] / sw;
    cs_s[q] = g1_s[q] / ss;
  }
  __syncthreads();

  // ---- prefetch first V fragment (hidden under build-W) ----
  const bf16_t* vrow = vtg + ((long)(b * 512 + h * 64 + w * 16 + l16)) * 800 + quad * 8;
  bf16x8 bv = *(const bf16x8*)vrow;

  // ---- build combined weight matrix W in place (b128; zero cols 784..799) ----
  for (int t = tid; t < 2800; t += 256){
    int q = t / 100;
    int c0 = (t - q * 100) * 8;
    uintx4 ov;
    if (c0 >= 784){
      ov = (uintx4){0u, 0u, 0u, 0u};
    } else {
      union { bf16_t hh[8]; uintx4 v; } in, out;
      in.v = *(uintx4*)&sbuf[q][c0];
      int iq = i0 + q;
      float cwv = cw_s[q], csv = cs_s[q];
      float cse = ((c0 >= 392) == (sel_s[q] != 0)) ? csv : 0.0f;
#pragma unroll
      for (int jj = 0; jj < 8; jj++){
        int c = c0 + jj;
        float coef = cse;
        if (c >= iq - 195 && c <= iq + 195) coef += cwv;
        out.hh[jj] = __float2bfloat16(__bfloat162float(in.hh[jj]) * coef);
      }
      ov = out.v;
    }
    *(uintx4*)&sbuf[q][c0] = ov;
  }
  __syncthreads();

  // ---- Phase D: out = W . V via MFMA, V fragments straight from global VT --------
  floatx4 o0 = (floatx4)(0.0f), o1 = (floatx4)(0.0f);
#pragma unroll 5
  for (int st = 0; st < 25; st++){
    bf16x8 bcur = bv;
    if (st + 1 < 25) bv = *(const bf16x8*)(vrow + (st + 1) * 32);
    int kc = st * 32 + quad * 8;
    bf16x8 av0 = *(bf16x8*)&sbuf[l16][kc];
    bf16x8 av1 = *(bf16x8*)&sbuf[16 + l16][kc];
    o0 = __builtin_amdgcn_mfma_f32_16x16x32_bf16(av0, bcur, o0, 0, 0, 0);
    o1 = __builtin_amdgcn_mfma_f32_16x16x32_bf16(av1, bcur, o1, 0, 0, 0);
  }

  // ---- epilogue: add compressed branch, write bf16 ----
  int d = w * 16 + l16;
#pragma unroll
  for (int reg = 0; reg < 4; reg++){
    int q = quad * 4 + reg;
    float o = o0[reg] + outc_s[q][d];
    oattn[((long)(b * SEQ_ + i0 + q)) * DIMC + h * 64 + d] = __float2bfloat16(o);
    int q2 = q + 16;
    if (q2 < 28){
      float o2 = o1[reg] + outc_s[q2][d];
      oattn[((long)(b * SEQ_ + i0 + q2)) * DIMC + h * 64 + d] = __float2bfloat16(o2);
    }
  }
}

// ---------------- host launcher ----------------
extern "C" void kernel_launch(void* const* d_in, const int* in_sizes, int n_in,
                              void* d_out, int out_size, void* d_ws, size_t ws_size,
                              hipStream_t stream){
  const float* xin  = (const float*)d_in[0];
  const float* pos  = (const float*)d_in[1];
  const float* angm = (const float*)d_in[2];
  const float* Wq   = (const float*)d_in[3];
  const float* Wk   = (const float*)d_in[4];
  const float* Wv   = (const float*)d_in[5];
  const float* Wo   = (const float*)d_in[6];
  const float* Wg   = (const float*)d_in[7];
  const float* fng  = (const float*)d_in[8];
  const float* fnb  = (const float*)d_in[9];
  const float* fw1  = (const float*)d_in[10];
  const float* fb1  = (const float*)d_in[11];
  const float* fw2  = (const float*)d_in[12];
  const float* fb2  = (const float*)d_in[13];

  // workspace layout: ~70.7 MB total (BUFb/H1b share one region — disjoint live ranges)
  char* cw = (char*)d_ws;
  float* X = (float*)cw;             cw += (long)NTOK * 512 * 4;     // 12.85 MB
  bf16_t* XRb = (bf16_t*)cw;         cw += (long)NTOK * 512 * 2;     //  6.42 MB
  bf16_t* OAb = (bf16_t*)cw;         cw += (long)NTOK * 512 * 2;     //  6.42 MB
  bf16_t* SH  = (bf16_t*)cw;         cw += (long)NTOK * FF_ * 2;     // 25.69 MB (BUFb/H1b)
  float* CK = (float*)cw;            cw += (long)B_ * NC_ * DIMC * 4;
  float* CV = (float*)cw;            cw += (long)B_ * NC_ * DIMC * 4;
  bf16_t* Wqkvgb = (bf16_t*)cw;      cw += (long)2 * QLD * 512 * 2;  //  3.19 MB
  bf16_t* WOb    = (bf16_t*)cw;      cw += (long)2 * 512 * 512 * 2;  //  1.05 MB
  bf16_t* FW1b   = (bf16_t*)cw;      cw += (long)2 * FF_ * 512 * 2;  //  4.19 MB
  bf16_t* FW2b   = (bf16_t*)cw;      cw += (long)2 * 512 * FF_ * 2;  //  4.19 MB
  bf16_t* VTb    = (bf16_t*)cw;      cw += (long)B_ * 512 * 800 * 2; //  6.55 MB
  bf16_t* BUFb = SH;   // [NTOK, QLD]  (QKVG output; dies after k_attn)
  bf16_t* H1b  = SH;   // [NTOK, FF_]  (FF1 output; born after k_ln)

  // per-call weight conversion (deterministic, same work every call)
  k_wconv1<<<(2 * QLD * 512) / 256, 256, 0, stream>>>(Wq, Wk, Wv, Wg, Wqkvgb);
  k_wconv2<<<(2 * 512 * 512) / 256, 256, 0, stream>>>(Wo, WOb);
  k_cast<<<(2 * FF_ * 512) / 256, 256, 0, stream>>>(fw1, FW1b);
  k_cast<<<(2 * 512 * FF_) / 256, 256, 0, stream>>>(fw2, FW2b);

  // zero VT once: tokens 784..799 stay zero; cols 0..783 rewritten each layer
  k_zero<<<1600, 256, 0, stream>>>((uintx4*)VTb);   // 6,553,600 B

  k_init<<<12544, 256, 0, stream>>>(xin, pos, X);

  for (int l = 0; l < 2; l++){
    k_rms<<<NTOK, 256, 0, stream>>>(X, angm + (long)l * DIMC, XRb);

    // fused QKV+G GEMM: [6272,512] x [1560,512]^T -> BUFb [6272,1560] bf16 (+ VT)
    k_mgemm<1, 0><<<49 * 13, 256, 0, stream>>>(
        XRb, Wqkvgb + (long)l * QLD * 512, nullptr, BUFb, nullptr, nullptr,
        NTOK, QLD, 512, QLD, 0, VTb);

    k_cpool<<<B_ * NC_, 512, 0, stream>>>(BUFb, CK, CV);

    k_attn<<<8 * 8 * 28, 256, 0, stream>>>(BUFb, CK, CV, VTb, OAb);

    // Wo GEMM: f32 out + residual into X
    k_mgemm<0, 0><<<49 * 4, 256, 0, stream>>>(
        OAb, WOb + (long)l * 512 * 512, X, nullptr, nullptr, X,
        NTOK, 512, 512, 512, 0, nullptr);

    k_ln<<<NTOK, 256, 0, stream>>>(X, fng + (long)l * DIMC, fnb + (long)l * DIMC, XRb);

    // FF1 + GELU, bf16 out into H1b
    k_mgemm<1, 1><<<49 * 16, 256, 0, stream>>>(
        XRb, FW1b + (long)l * FF_ * 512, nullptr, H1b, fb1 + (long)l * FF_, nullptr,
        NTOK, FF_, 512, FF_, 0, nullptr);
    // FF2, f32 out + residual into X
    k_mgemm<0, 0><<<49 * 4, 256, 0, stream>>>(
        H1b, FW2b + (long)l * 512 * FF_, X, nullptr, fb2 + (long)l * DIMC, X,
        NTOK, 512, FF_, 512, 0, nullptr);
  }

  k_final<<<12544, 256, 0, stream>>>(X, (float*)d_out);
}

// Round 3
// 660.200 us; speedup vs baseline: 1.1871x; 1.1871x over previous
//
#include <hip/hip_runtime.h>
#include <hip/hip_bf16.h>
#include <math.h>

// ---- static config (matches reference) ----
#define B_      8
#define DIMC    512
#define SEQ_    784
#define HEADS_  8
#define DH_     64
#define NTOK    (B_*SEQ_)      // 6272
#define QLD     1560           // q(512) | k(512) | v(512) | gates(24)
#define WIN_    196
#define CBS_    392
#define CST_    196
#define NC_     3
#define EPSF    1e-5f
#define FF_     2048
#define TQ_     28             // queries per block (28*28 = 784)
#define MT_     98             // m-tiles (6272/64)

typedef __hip_bfloat16 bf16_t;
typedef __attribute__((ext_vector_type(8))) short bf16x8;
typedef __attribute__((ext_vector_type(4))) float floatx4;
typedef __attribute__((ext_vector_type(4))) unsigned int uintx4;
typedef __attribute__((ext_vector_type(2))) unsigned int uintx2;

// ---------------- helpers ----------------
__device__ __forceinline__ float wsum(float x){
#pragma unroll
  for (int o = 32; o; o >>= 1) x += __shfl_xor(x, o, 64);
  return x;
}
__device__ __forceinline__ float geluf(float x){
  return 0.5f * x * (1.0f + erff(x * 0.70710678118654752f));
}
__device__ __forceinline__ float sigmoidf_(float x){
  return 1.0f / (1.0f + __expf(-x));
}

// ---------------- init: x[b,c,h,w] (f32) -> X[b,p,c] (f32) + pos ----------------
__global__ __launch_bounds__(256) void k_init(const float* __restrict__ xin,
                                              const float* __restrict__ pos,
                                              float* __restrict__ X){
  int idx = blockIdx.x * 256 + threadIdx.x;       // over NTOK*512 (exact)
  int c = idx & 511;
  int t = idx >> 9;          // b*784 + p
  int p = t % SEQ_;
  int b = t / SEQ_;
  float v = xin[((long)(b * DIMC + c)) * SEQ_ + p];
  X[idx] = v + pos[p];
}

// ---------------- final: X[b,p,c] -> out[b,c,h,w] f32 ----------------
__global__ __launch_bounds__(256) void k_final(const float* __restrict__ X,
                                               float* __restrict__ out){
  int idx = blockIdx.x * 256 + threadIdx.x;       // over B*DIMC*SEQ (exact)
  int p = idx % SEQ_;
  int t = idx / SEQ_;        // b*512 + c
  int c = t & 511;
  int b = t >> 9;
  out[idx] = X[((long)(b * SEQ_ + p)) * DIMC + c];
}

// ---------------- weight conversion: WQKVG [l][n 0..1559][k 0..511] bf16 (transposed) ----
__global__ __launch_bounds__(256) void k_wconv1(const float* __restrict__ Wq,
                                                const float* __restrict__ Wk,
                                                const float* __restrict__ Wv,
                                                const float* __restrict__ Wg,
                                                bf16_t* __restrict__ Wb){
  int idx = blockIdx.x * 256 + threadIdx.x;   // over 2*1560*512 (6240 blocks, exact)
  int k = idx & 511;
  int t = idx >> 9;
  int n = t % QLD;
  int l = t / QLD;
  float v;
  if (n < 1536){
    int which = n >> 9;
    int nn = n & 511;
    const float* W = (which == 0) ? Wq : ((which == 1) ? Wk : Wv);
    v = W[((long)(l * 512 + k)) * 512 + nn];
  } else {
    v = Wg[((long)(l * 512 + k)) * 24 + (n - 1536)];
  }
  Wb[idx] = __float2bfloat16(v);
}

// ---------------- WO transpose: Wb[l][n][k] = Wo[l][k][n] ----------------
__global__ __launch_bounds__(256) void k_wconv2(const float* __restrict__ Wo,
                                                bf16_t* __restrict__ Wb){
  int idx = blockIdx.x * 256 + threadIdx.x;   // over 2*512*512 (2048 blocks)
  int k = idx & 511;
  int t = idx >> 9;
  int n = t & 511;
  int l = t >> 9;
  Wb[idx] = __float2bfloat16(Wo[((long)(l * 512 + k)) * 512 + n]);
}

// ---------------- plain f32 -> bf16 cast ----------------
__global__ __launch_bounds__(256) void k_cast(const float* __restrict__ src,
                                              bf16_t* __restrict__ dst){
  int idx = blockIdx.x * 256 + threadIdx.x;
  dst[idx] = __float2bfloat16(src[idx]);
}

// ---------------- 16B-granular zero fill ----------------
__global__ __launch_bounds__(256) void k_zero(uintx4* __restrict__ p){
  p[blockIdx.x * 256 + threadIdx.x] = (uintx4){0u, 0u, 0u, 0u};
}

// ---------------- RMSNorm: f32 in -> bf16 out ----------------
__global__ __launch_bounds__(256) void k_rms(const float* __restrict__ X,
                                             const float* __restrict__ g,
                                             bf16_t* __restrict__ XR){
  int tok = blockIdx.x;
  int tid = threadIdx.x;
  const float* xr = X + (long)tok * DIMC;
  float v0 = xr[tid], v1 = xr[tid + 256];
  float ss = v0 * v0 + v1 * v1;
  ss = wsum(ss);
  __shared__ float red[4];
  if ((tid & 63) == 0) red[tid >> 6] = ss;
  __syncthreads();
  float tot = red[0] + red[1] + red[2] + red[3];
  float r = rsqrtf(tot * (1.0f / DIMC) + EPSF);
  XR[(long)tok * DIMC + tid]       = __float2bfloat16(v0 * r * g[tid]);
  XR[(long)tok * DIMC + tid + 256] = __float2bfloat16(v1 * r * g[tid + 256]);
}

// ---------------- LayerNorm: f32 in -> bf16 out ----------------
__global__ __launch_bounds__(256) void k_ln(const float* __restrict__ X,
                                            const float* __restrict__ g,
                                            const float* __restrict__ bb,
                                            bf16_t* __restrict__ XN){
  int tok = blockIdx.x;
  int tid = threadIdx.x;
  const float* xr = X + (long)tok * DIMC;
  float v0 = xr[tid], v1 = xr[tid + 256];
  float s = v0 + v1;
  float q = v0 * v0 + v1 * v1;
  s = wsum(s); q = wsum(q);
  __shared__ float r1[4], r2[4];
  if ((tid & 63) == 0){ r1[tid >> 6] = s; r2[tid >> 6] = q; }
  __syncthreads();
  float ts = r1[0] + r1[1] + r1[2] + r1[3];
  float tq = r2[0] + r2[1] + r2[2] + r2[3];
  float mean = ts * (1.0f / DIMC);
  float var  = tq * (1.0f / DIMC) - mean * mean;
  float rinv = rsqrtf(var + EPSF);
  XN[(long)tok * DIMC + tid]       = __float2bfloat16((v0 - mean) * rinv * g[tid]       + bb[tid]);
  XN[(long)tok * DIMC + tid + 256] = __float2bfloat16((v1 - mean) * rinv * g[tid + 256] + bb[tid + 256]);
}

// ---------------- bf16 MFMA GEMM: R1 64x64 structure + prefetch-after-barrier -------
// __syncthreads drains vmcnt(0): issuing the next-chunk global loads BEFORE the
// barrier exposed full L2 latency every chunk. Issue them AFTER the barrier so
// they fly under this chunk's ds_read+MFMA and are landed by the next barrier.
// VTo != nullptr (QKVG GEMM only): also write V columns (ncol in [1024,1536))
// transposed to VTo[b*512 + d][tok] (bf16, row width 800; cols 784..799 pre-zeroed).
template<int OUTBF, int ACT>
__global__ __launch_bounds__(256) void k_mgemm(const bf16_t* __restrict__ A,
                                               const bf16_t* __restrict__ Bm,
                                               float* Cf,
                                               bf16_t* Cb,
                                               const float* __restrict__ bias,
                                               const float* res,
                                               int M, int N, int K, int ldc, int ccol,
                                               bf16_t* VTo){
  int id = blockIdx.x;
  int xcd = id & 7;
  int j = id >> 3;
  int nt = j / 13;
  int mt = xcd * 13 + (j - nt * 13);
  if (mt >= MT_) return;
  int bm = mt * 64, bn = nt * 64;

  __shared__ bf16_t As[2][64][40];   // 32 k + 8 pad, double-buffered
  __shared__ bf16_t Bs[2][64][40];
  int tid = threadIdx.x;
  int w = tid >> 6, lane = tid & 63;
  int wm = (w & 1) * 32, wn = (w >> 1) * 32;
  int quad = lane >> 4, l16 = lane & 15;

  int lrow = tid >> 2, lkc = (tid & 3) * 8;
  bool bok = (bn + lrow) < N;
  const bf16_t* ap = A + (long)(bm + lrow) * K + lkc;
  const bf16_t* bp = Bm + (long)(bok ? bn + lrow : 0) * K + lkc;

  floatx4 acc[2][2];
#pragma unroll
  for (int i = 0; i < 2; i++)
#pragma unroll
    for (int jj = 0; jj < 2; jj++) acc[i][jj] = (floatx4)(0.0f);

  uintx4 areg = *(const uintx4*)ap;
  uintx4 breg = *(const uintx4*)bp;
  if (!bok) breg = (uintx4){0u,0u,0u,0u};

  int nch = K >> 5;
  for (int ch = 0; ch < nch; ch++){
    int buf = ch & 1;
    *(uintx4*)&As[buf][lrow][lkc] = areg;
    *(uintx4*)&Bs[buf][lrow][lkc] = breg;
    __syncthreads();
    // prefetch AFTER the barrier: latency hides under this chunk's compute and
    // has landed by the time the next barrier drains vmcnt.
    if (ch + 1 < nch){
      areg = *(const uintx4*)(ap + (ch + 1) * 32);
      breg = *(const uintx4*)(bp + (ch + 1) * 32);
      if (!bok) breg = (uintx4){0u,0u,0u,0u};
    }
    bf16x8 a0 = *(bf16x8*)&As[buf][wm + l16][quad * 8];
    bf16x8 a1 = *(bf16x8*)&As[buf][wm + 16 + l16][quad * 8];
    bf16x8 b0 = *(bf16x8*)&Bs[buf][wn + l16][quad * 8];
    bf16x8 b1 = *(bf16x8*)&Bs[buf][wn + 16 + l16][quad * 8];
    acc[0][0] = __builtin_amdgcn_mfma_f32_16x16x32_bf16(a0, b0, acc[0][0], 0, 0, 0);
    acc[0][1] = __builtin_amdgcn_mfma_f32_16x16x32_bf16(a0, b1, acc[0][1], 0, 0, 0);
    acc[1][0] = __builtin_amdgcn_mfma_f32_16x16x32_bf16(a1, b0, acc[1][0], 0, 0, 0);
    acc[1][1] = __builtin_amdgcn_mfma_f32_16x16x32_bf16(a1, b1, acc[1][1], 0, 0, 0);
    // no trailing barrier: next iter writes the other buffer; re-write of this
    // buffer happens only after the next barrier, which is after all reads here.
  }
#pragma unroll
  for (int tm = 0; tm < 2; tm++){
#pragma unroll
    for (int tn = 0; tn < 2; tn++){
      int ncol = bn + wn + tn * 16 + l16;
      if (ncol >= N) continue;
#pragma unroll
      for (int reg = 0; reg < 4; reg++){
        long mrow = bm + wm + tm * 16 + quad * 4 + reg;
        float v = acc[tm][tn][reg];
        if (bias) v += bias[ncol];
        if (ACT == 1) v = geluf(v);
        long off = mrow * (long)ldc + ccol + ncol;
        if (res) v += res[off];
        if (OUTBF){
          Cb[off] = __float2bfloat16(v);
          if (VTo && ncol >= 1024 && ncol < 1536){
            int bb2 = (int)(mrow / SEQ_);
            int tok = (int)(mrow - (long)bb2 * SEQ_);
            VTo[((long)(bb2 * 512 + (ncol - 1024))) * 800 + tok] = __float2bfloat16(v);
          }
        }
        else       Cf[off] = v;
      }
    }
  }
}

// ---------------- compressed-block mean pooling, vectorized + coalesced -------------
__global__ __launch_bounds__(512) void k_cpool(const bf16_t* __restrict__ qkvg,
                                               float* __restrict__ ck,
                                               float* __restrict__ cv){
  int bj = blockIdx.x;
  int j = bj % NC_;
  int b = bj / NC_;
  int tid = threadIdx.x;
  int seg = tid & 127;
  int rg  = tid >> 7;
  __shared__ float part[4][1024];
  const bf16_t* base = qkvg + ((long)b * SEQ_ + (long)j * CST_) * QLD + 512;
  float acc[8] = {0.f,0.f,0.f,0.f,0.f,0.f,0.f,0.f};
  for (int r = rg; r < CBS_; r += 4){
    uintx4 v = *(const uintx4*)(base + (long)r * QLD + seg * 8);
    bf16_t tmp[8]; *(uintx4*)tmp = v;
#pragma unroll
    for (int q = 0; q < 8; q++) acc[q] += __bfloat162float(tmp[q]);
  }
#pragma unroll
  for (int q = 0; q < 8; q++) part[rg][seg * 8 + q] = acc[q];
  __syncthreads();
  for (int c = tid; c < 1024; c += 512){
    float s = (part[0][c] + part[1][c]) + (part[2][c] + part[3][c]);
    s *= (1.0f / CBS_);
    if (c < 512) ck[bj * DIMC + c] = s;
    else         cv[bj * DIMC + (c - 512)] = s;
  }
}

// ---------------- fused NSA attention v7: v6 + prefetch-after-barrier in Phase C ----
__global__ __launch_bounds__(256) void k_attn(const bf16_t* __restrict__ qkvg,
                                              const float* __restrict__ ck,
                                              const float* __restrict__ cv,
                                              const bf16_t* __restrict__ vtg,
                                              bf16_t* __restrict__ oattn){
  int tid = threadIdx.x;
  int w = tid >> 6, lane = tid & 63;
  int quad = lane >> 4, l16 = lane & 15;
  int id = blockIdx.x;
  int xcd = id & 7;
  int j = id >> 3;               // 0..223
  int bh = xcd * 8 + (j / 28);   // all 28 tiles of a bh on one XCD
  int i0 = (j % 28) * TQ_;
  int h = bh & 7, b = bh >> 3;
  const float scale = 0.125f;

  __shared__ __align__(16) char smem[77040];
  bf16_t (*Qs)[72]    = (bf16_t(*)[72])(smem);             // 4608 B (rows 28-31 zero)
  bf16_t (*Ks0)[72]   = (bf16_t(*)[72])(smem + 4608);      // 9216 B (dbuf 0, 64 keys)
  bf16_t (*Ks1)[72]   = (bf16_t(*)[72])(smem + 13824);     // 9216 B (dbuf 1)
  bf16_t (*sbuf)[808] = (bf16_t(*)[808])(smem + 23040);    // 45248 B
  float  (*outc_s)[64]= (float(*)[64])(smem + 68288);      // 7168 B (absorbs overreads)
  int*   sel_s = (int*)(smem + 75456);                     // 112 B
  float* cw_s  = (float*)(smem + 75568);                   // 112 B
  float* cs_s  = (float*)(smem + 75680);                   // 112 B
  float* g1_s  = (float*)(smem + 75792);                   // 112 B
  float* g2_s  = (float*)(smem + 75904);                   // 112 B
  float (*red_s)[4][16] = (float(*)[4][16])(smem + 76016); // 1024 B

  const long rowBase = (long)b * SEQ_ * QLD + h * 64;     // + token*QLD + {0,512,1024}

  // ---- Phase A: stage Q tile (28 rows) + zero rows 28-31 ----
  if (tid < 224){
    int q = tid >> 3, seg = tid & 7;
    uintx4 qv = *(const uintx4*)(qkvg + rowBase + (long)(i0 + q) * QLD + seg * 8);
    *(uintx4*)&Qs[q][seg * 8] = qv;
  } else {
    int u = tid - 224;
    int r = 28 + (u >> 3), seg = u & 7;
    *(uintx4*)&Qs[r][seg * 8] = (uintx4){0u, 0u, 0u, 0u};
  }
  __syncthreads();

  // ---- prefetch K chunk 0 (latency hidden under Phase B) ----
  int r0i = tid >> 3, s0i = tid & 7;
  int r1i = 32 + r0i;
  uintx4 kreg0 = *(const uintx4*)(qkvg + rowBase + (long)r0i * QLD + 512 + s0i * 8);
  uintx4 kreg1 = *(const uintx4*)(qkvg + rowBase + (long)r1i * QLD + 512 + s0i * 8);

  // ---- Phase B: compressed branch + gates + top-1 selection ----
  {
    const float* CKp = ck + (long)b * NC_ * DIMC + h * 64 + lane;
    const float* CVp = cv + (long)b * NC_ * DIMC + h * 64 + lane;
    float k0 = CKp[0], k1 = CKp[512], k2 = CKp[1024];
    float v0 = CVp[0], v1 = CVp[512], v2 = CVp[1024];
#pragma unroll
    for (int qp = 0; qp < 7; qp++){
      int qg = w * 7 + qp;
      float qd = __bfloat162float(Qs[qg][lane]);
      float s0 = wsum(qd * k0) * scale;
      float s1 = wsum(qd * k1) * scale;
      float s2 = wsum(qd * k2) * scale;
      float m3 = fmaxf(s0, fmaxf(s1, s2));
      float e0 = __expf(s0 - m3), e1 = __expf(s1 - m3), e2 = __expf(s2 - m3);
      float inv = 1.0f / (e0 + e1 + e2);
      const bf16_t* grow = qkvg + (long)(b * SEQ_ + i0 + qg) * QLD + 1536 + h * 3;
      float g0 = sigmoidf_(__bfloat162float(grow[0]));
      float g1v = sigmoidf_(__bfloat162float(grow[1]));
      float g2v = sigmoidf_(__bfloat162float(grow[2]));
      outc_s[qg][lane] = g0 * (e0 * v0 + e1 * v1 + e2 * v2) * inv;
      int selv = (s2 > s0) ? 1 : 0;   // imp1>imp0 <=> p2>p0 <=> s2>s0
      if (lane == 0){ sel_s[qg] = selv; g1_s[qg] = g1v; g2_s[qg] = g2v; }
    }
  }

  // hoist Q B-fragments (chunk-invariant)
  bf16x8 a00 = *(bf16x8*)&Qs[l16][quad * 8];
  bf16x8 a01 = *(bf16x8*)&Qs[l16][32 + quad * 8];
  bf16x8 a10 = *(bf16x8*)&Qs[16 + l16][quad * 8];
  bf16x8 a11 = *(bf16x8*)&Qs[16 + l16][32 + quad * 8];

  __syncthreads();   // sel_s/g1_s/g2_s/outc_s visible to all waves

  // ---- Phase C: S^T = K.Q^T via MFMA (13 chunks of 64 keys, dbuf) ----------------
  // Lane (quad,l16) of wave w holds keys ch*64 + w*16 + quad*4 + {0..3} for
  // q = l16 (d0) and q = 16+l16 (d1): packed b64 score stores + in-reg row sums.
  // Prefetch issued AFTER the barrier (see k_mgemm note).
  int sel0i = sel_s[l16];
  int sel1i = (l16 < 12) ? sel_s[16 + l16] : 0;
  bool sv0 = (sel0i != 0), sv1 = (sel1i != 0);
  int iq0 = i0 + l16, iq1 = i0 + 16 + l16;
  float sw0 = 0.f, ss0 = 0.f, sw1 = 0.f, ss1 = 0.f;

  for (int ch = 0; ch < 13; ch++){
    bf16_t (*Kb)[72] = (ch & 1) ? Ks1 : Ks0;
    *(uintx4*)&Kb[r0i][s0i * 8] = kreg0;
    *(uintx4*)&Kb[r1i][s0i * 8] = kreg1;
    __syncthreads();
    if (ch + 1 < 13){
      int c0n = (ch + 1) * 64;
      int t0 = c0n + r0i; if (t0 > 783) t0 = 783;
      int t1 = c0n + r1i; if (t1 > 783) t1 = 783;
      kreg0 = *(const uintx4*)(qkvg + rowBase + (long)t0 * QLD + 512 + s0i * 8);
      kreg1 = *(const uintx4*)(qkvg + rowBase + (long)t1 * QLD + 512 + s0i * 8);
    }
    bf16x8 k0 = *(bf16x8*)&Kb[w * 16 + l16][quad * 8];
    bf16x8 k1 = *(bf16x8*)&Kb[w * 16 + l16][32 + quad * 8];
    floatx4 d0 = (floatx4)(0.0f), d1 = (floatx4)(0.0f);
    d0 = __builtin_amdgcn_mfma_f32_16x16x32_bf16(k0, a00, d0, 0, 0, 0);
    d0 = __builtin_amdgcn_mfma_f32_16x16x32_bf16(k1, a01, d0, 0, 0, 0);
    d1 = __builtin_amdgcn_mfma_f32_16x16x32_bf16(k0, a10, d1, 0, 0, 0);
    d1 = __builtin_amdgcn_mfma_f32_16x16x32_bf16(k1, a11, d1, 0, 0, 0);
    int kb = ch * 64 + w * 16 + quad * 4;
    union { bf16_t hh[4]; uintx2 v; } p0, p1;
#pragma unroll
    for (int r = 0; r < 4; r++){
      int key = kb + r;
      float ex0 = __expf(d0[r] * scale);
      float ex1 = __expf(d1[r] * scale);
      bool valid = key < 784;
      if (valid && key >= iq0 - 195 && key <= iq0 + 195) sw0 += ex0;
      if (valid && ((key >= 392) == sv0))                ss0 += ex0;
      if (valid && key >= iq1 - 195 && key <= iq1 + 195) sw1 += ex1;
      if (valid && ((key >= 392) == sv1))                ss1 += ex1;
      p0.hh[r] = __float2bfloat16(ex0);
      p1.hh[r] = __float2bfloat16(ex1);
    }
    if (kb < 784){
      *(uintx2*)&sbuf[l16][kb] = p0.v;
      if (l16 < 12) *(uintx2*)&sbuf[16 + l16][kb] = p1.v;
    }
  }

  // ---- combine row sums: quads via shfl, waves via 1KB LDS ----
  sw0 += __shfl_xor(sw0, 16, 64); sw0 += __shfl_xor(sw0, 32, 64);
  ss0 += __shfl_xor(ss0, 16, 64); ss0 += __shfl_xor(ss0, 32, 64);
  sw1 += __shfl_xor(sw1, 16, 64); sw1 += __shfl_xor(sw1, 32, 64);
  ss1 += __shfl_xor(ss1, 16, 64); ss1 += __shfl_xor(ss1, 32, 64);
  if (quad == 0){
    red_s[w][0][l16] = sw0; red_s[w][1][l16] = ss0;
    red_s[w][2][l16] = sw1; red_s[w][3][l16] = ss1;
  }
  __syncthreads();
  if (tid < 28){
    int q = tid, t = q >> 4, l = q & 15;
    float sw = 0.f, ss = 0.f;
#pragma unroll
    for (int wv = 0; wv < 4; wv++){ sw += red_s[wv][2 * t][l]; ss += red_s[wv][2 * t + 1][l]; }
    cw_s[q] = g2_s[q] / sw;
    cs_s[q] = g1_s[q] / ss;
  }
  __syncthreads();

  // ---- prefetch first V fragment (hidden under build-W) ----
  const bf16_t* vrow = vtg + ((long)(b * 512 + h * 64 + w * 16 + l16)) * 800 + quad * 8;
  bf16x8 bv = *(const bf16x8*)vrow;

  // ---- build combined weight matrix W in place (b128; zero cols 784..799) ----
  for (int t = tid; t < 2800; t += 256){
    int q = t / 100;
    int c0 = (t - q * 100) * 8;
    uintx4 ov;
    if (c0 >= 784){
      ov = (uintx4){0u, 0u, 0u, 0u};
    } else {
      union { bf16_t hh[8]; uintx4 v; } in, out;
      in.v = *(uintx4*)&sbuf[q][c0];
      int iq = i0 + q;
      float cwv = cw_s[q], csv = cs_s[q];
      float cse = ((c0 >= 392) == (sel_s[q] != 0)) ? csv : 0.0f;
#pragma unroll
      for (int jj = 0; jj < 8; jj++){
        int c = c0 + jj;
        float coef = cse;
        if (c >= iq - 195 && c <= iq + 195) coef += cwv;
        out.hh[jj] = __float2bfloat16(__bfloat162float(in.hh[jj]) * coef);
      }
      ov = out.v;
    }
    *(uintx4*)&sbuf[q][c0] = ov;
  }
  __syncthreads();

  // ---- Phase D: out = W . V via MFMA, V fragments straight from global VT --------
  floatx4 o0 = (floatx4)(0.0f), o1 = (floatx4)(0.0f);
#pragma unroll 5
  for (int st = 0; st < 25; st++){
    bf16x8 bcur = bv;
    if (st + 1 < 25) bv = *(const bf16x8*)(vrow + (st + 1) * 32);
    int kc = st * 32 + quad * 8;
    bf16x8 av0 = *(bf16x8*)&sbuf[l16][kc];
    bf16x8 av1 = *(bf16x8*)&sbuf[16 + l16][kc];
    o0 = __builtin_amdgcn_mfma_f32_16x16x32_bf16(av0, bcur, o0, 0, 0, 0);
    o1 = __builtin_amdgcn_mfma_f32_16x16x32_bf16(av1, bcur, o1, 0, 0, 0);
  }

  // ---- epilogue: add compressed branch, write bf16 ----
  int d = w * 16 + l16;
#pragma unroll
  for (int reg = 0; reg < 4; reg++){
    int q = quad * 4 + reg;
    float o = o0[reg] + outc_s[q][d];
    oattn[((long)(b * SEQ_ + i0 + q)) * DIMC + h * 64 + d] = __float2bfloat16(o);
    int q2 = q + 16;
    if (q2 < 28){
      float o2 = o1[reg] + outc_s[q2][d];
      oattn[((long)(b * SEQ_ + i0 + q2)) * DIMC + h * 64 + d] = __float2bfloat16(o2);
    }
  }
}

// ---------------- host launcher ----------------
extern "C" void kernel_launch(void* const* d_in, const int* in_sizes, int n_in,
                              void* d_out, int out_size, void* d_ws, size_t ws_size,
                              hipStream_t stream){
  const float* xin  = (const float*)d_in[0];
  const float* pos  = (const float*)d_in[1];
  const float* angm = (const float*)d_in[2];
  const float* Wq   = (const float*)d_in[3];
  const float* Wk   = (const float*)d_in[4];
  const float* Wv   = (const float*)d_in[5];
  const float* Wo   = (const float*)d_in[6];
  const float* Wg   = (const float*)d_in[7];
  const float* fng  = (const float*)d_in[8];
  const float* fnb  = (const float*)d_in[9];
  const float* fw1  = (const float*)d_in[10];
  const float* fb1  = (const float*)d_in[11];
  const float* fw2  = (const float*)d_in[12];
  const float* fb2  = (const float*)d_in[13];

  // workspace layout: ~70.7 MB total (BUFb/H1b share one region — disjoint live ranges)
  char* cw = (char*)d_ws;
  float* X = (float*)cw;             cw += (long)NTOK * 512 * 4;     // 12.85 MB
  bf16_t* XRb = (bf16_t*)cw;         cw += (long)NTOK * 512 * 2;     //  6.42 MB
  bf16_t* OAb = (bf16_t*)cw;         cw += (long)NTOK * 512 * 2;     //  6.42 MB
  bf16_t* SH  = (bf16_t*)cw;         cw += (long)NTOK * FF_ * 2;     // 25.69 MB (BUFb/H1b)
  float* CK = (float*)cw;            cw += (long)B_ * NC_ * DIMC * 4;
  float* CV = (float*)cw;            cw += (long)B_ * NC_ * DIMC * 4;
  bf16_t* Wqkvgb = (bf16_t*)cw;      cw += (long)2 * QLD * 512 * 2;  //  3.19 MB
  bf16_t* WOb    = (bf16_t*)cw;      cw += (long)2 * 512 * 512 * 2;  //  1.05 MB
  bf16_t* FW1b   = (bf16_t*)cw;      cw += (long)2 * FF_ * 512 * 2;  //  4.19 MB
  bf16_t* FW2b   = (bf16_t*)cw;      cw += (long)2 * 512 * FF_ * 2;  //  4.19 MB
  bf16_t* VTb    = (bf16_t*)cw;      cw += (long)B_ * 512 * 800 * 2; //  6.55 MB
  bf16_t* BUFb = SH;   // [NTOK, QLD]  (QKVG output; dies after k_attn)
  bf16_t* H1b  = SH;   // [NTOK, FF_]  (FF1 output; born after k_ln)

  // per-call weight conversion (deterministic, same work every call)
  k_wconv1<<<(2 * QLD * 512) / 256, 256, 0, stream>>>(Wq, Wk, Wv, Wg, Wqkvgb);
  k_wconv2<<<(2 * 512 * 512) / 256, 256, 0, stream>>>(Wo, WOb);
  k_cast<<<(2 * FF_ * 512) / 256, 256, 0, stream>>>(fw1, FW1b);
  k_cast<<<(2 * 512 * FF_) / 256, 256, 0, stream>>>(fw2, FW2b);

  // zero VT once: tokens 784..799 stay zero; cols 0..783 rewritten each layer
  k_zero<<<1600, 256, 0, stream>>>((uintx4*)VTb);   // 6,553,600 B

  k_init<<<12544, 256, 0, stream>>>(xin, pos, X);

  for (int l = 0; l < 2; l++){
    k_rms<<<NTOK, 256, 0, stream>>>(X, angm + (long)l * DIMC, XRb);

    // fused QKV+G GEMM: [6272,512] x [1560,512]^T -> BUFb [6272,1560] bf16 (+ VT)
    k_mgemm<1, 0><<<25 * 104, 256, 0, stream>>>(
        XRb, Wqkvgb + (long)l * QLD * 512, nullptr, BUFb, nullptr, nullptr,
        NTOK, QLD, 512, QLD, 0, VTb);

    k_cpool<<<B_ * NC_, 512, 0, stream>>>(BUFb, CK, CV);

    k_attn<<<8 * 8 * 28, 256, 0, stream>>>(BUFb, CK, CV, VTb, OAb);

    // Wo GEMM: f32 out + residual into X
    k_mgemm<0, 0><<<8 * 104, 256, 0, stream>>>(
        OAb, WOb + (long)l * 512 * 512, X, nullptr, nullptr, X,
        NTOK, 512, 512, 512, 0, nullptr);

    k_ln<<<NTOK, 256, 0, stream>>>(X, fng + (long)l * DIMC, fnb + (long)l * DIMC, XRb);

    // FF1 + GELU, bf16 out into H1b
    k_mgemm<1, 1><<<32 * 104, 256, 0, stream>>>(
        XRb, FW1b + (long)l * FF_ * 512, nullptr, H1b, fb1 + (long)l * FF_, nullptr,
        NTOK, FF_, 512, FF_, 0, nullptr);
    // FF2, f32 out + residual into X
    k_mgemm<0, 0><<<8 * 104, 256, 0, stream>>>(
        H1b, FW2b + (long)l * 512 * FF_, X, nullptr, fb2 + (long)l * DIMC, X,
        NTOK, 512, FF_, 512, 0, nullptr);
  }

  k_final<<<12544, 256, 0, stream>>>(X, (float*)d_out);
}

// Round 4
// 651.100 us; speedup vs baseline: 1.2037x; 1.0140x over previous
//
#include <hip/hip_runtime.h>
#include <hip/hip_bf16.h>
#include <math.h>

// ---- static config (matches reference) ----
#define B_      8
#define DIMC    512
#define SEQ_    784
#define HEADS_  8
#define DH_     64
#define NTOK    (B_*SEQ_)      // 6272
#define QLD     1560           // q(512) | k(512) | v(512) | gates(24)
#define WIN_    196
#define CBS_    392
#define CST_    196
#define NC_     3
#define EPSF    1e-5f
#define FF_     2048
#define TQ_     28             // queries per block (28*28 = 784)
#define MT_     98             // m-tiles (6272/64)

typedef __hip_bfloat16 bf16_t;
typedef __attribute__((ext_vector_type(8))) short bf16x8;
typedef __attribute__((ext_vector_type(4))) float floatx4;
typedef __attribute__((ext_vector_type(4))) unsigned int uintx4;
typedef __attribute__((ext_vector_type(2))) unsigned int uintx2;

// ---------------- helpers ----------------
__device__ __forceinline__ float wsum(float x){
#pragma unroll
  for (int o = 32; o; o >>= 1) x += __shfl_xor(x, o, 64);
  return x;
}
__device__ __forceinline__ float geluf(float x){
  return 0.5f * x * (1.0f + erff(x * 0.70710678118654752f));
}
__device__ __forceinline__ float sigmoidf_(float x){
  return 1.0f / (1.0f + __expf(-x));
}

// ---------------- init: x[b,c,h,w] (f32) -> X[b,p,c] (f32) + pos ----------------
__global__ __launch_bounds__(256) void k_init(const float* __restrict__ xin,
                                              const float* __restrict__ pos,
                                              float* __restrict__ X){
  int idx = blockIdx.x * 256 + threadIdx.x;       // over NTOK*512 (exact)
  int c = idx & 511;
  int t = idx >> 9;          // b*784 + p
  int p = t % SEQ_;
  int b = t / SEQ_;
  float v = xin[((long)(b * DIMC + c)) * SEQ_ + p];
  X[idx] = v + pos[p];
}

// ---------------- final: X[b,p,c] -> out[b,c,h,w] f32 ----------------
__global__ __launch_bounds__(256) void k_final(const float* __restrict__ X,
                                               float* __restrict__ out){
  int idx = blockIdx.x * 256 + threadIdx.x;       // over B*DIMC*SEQ (exact)
  int p = idx % SEQ_;
  int t = idx / SEQ_;        // b*512 + c
  int c = t & 511;
  int b = t >> 9;
  out[idx] = X[((long)(b * SEQ_ + p)) * DIMC + c];
}

// ---------------- weight conversion: WQKVG [l][n 0..1559][k 0..511] bf16 (transposed) ----
__global__ __launch_bounds__(256) void k_wconv1(const float* __restrict__ Wq,
                                                const float* __restrict__ Wk,
                                                const float* __restrict__ Wv,
                                                const float* __restrict__ Wg,
                                                bf16_t* __restrict__ Wb){
  int idx = blockIdx.x * 256 + threadIdx.x;   // over 2*1560*512 (6240 blocks, exact)
  int k = idx & 511;
  int t = idx >> 9;
  int n = t % QLD;
  int l = t / QLD;
  float v;
  if (n < 1536){
    int which = n >> 9;
    int nn = n & 511;
    const float* W = (which == 0) ? Wq : ((which == 1) ? Wk : Wv);
    v = W[((long)(l * 512 + k)) * 512 + nn];
  } else {
    v = Wg[((long)(l * 512 + k)) * 24 + (n - 1536)];
  }
  Wb[idx] = __float2bfloat16(v);
}

// ---------------- WO transpose: Wb[l][n][k] = Wo[l][k][n] ----------------
__global__ __launch_bounds__(256) void k_wconv2(const float* __restrict__ Wo,
                                                bf16_t* __restrict__ Wb){
  int idx = blockIdx.x * 256 + threadIdx.x;   // over 2*512*512 (2048 blocks)
  int k = idx & 511;
  int t = idx >> 9;
  int n = t & 511;
  int l = t >> 9;
  Wb[idx] = __float2bfloat16(Wo[((long)(l * 512 + k)) * 512 + n]);
}

// ---------------- plain f32 -> bf16 cast ----------------
__global__ __launch_bounds__(256) void k_cast(const float* __restrict__ src,
                                              bf16_t* __restrict__ dst){
  int idx = blockIdx.x * 256 + threadIdx.x;
  dst[idx] = __float2bfloat16(src[idx]);
}

// ---------------- 16B-granular zero fill ----------------
__global__ __launch_bounds__(256) void k_zero(uintx4* __restrict__ p){
  p[blockIdx.x * 256 + threadIdx.x] = (uintx4){0u, 0u, 0u, 0u};
}

// ---------------- RMSNorm: f32 in -> bf16 out ----------------
__global__ __launch_bounds__(256) void k_rms(const float* __restrict__ X,
                                             const float* __restrict__ g,
                                             bf16_t* __restrict__ XR){
  int tok = blockIdx.x;
  int tid = threadIdx.x;
  const float* xr = X + (long)tok * DIMC;
  float v0 = xr[tid], v1 = xr[tid + 256];
  float ss = v0 * v0 + v1 * v1;
  ss = wsum(ss);
  __shared__ float red[4];
  if ((tid & 63) == 0) red[tid >> 6] = ss;
  __syncthreads();
  float tot = red[0] + red[1] + red[2] + red[3];
  float r = rsqrtf(tot * (1.0f / DIMC) + EPSF);
  XR[(long)tok * DIMC + tid]       = __float2bfloat16(v0 * r * g[tid]);
  XR[(long)tok * DIMC + tid + 256] = __float2bfloat16(v1 * r * g[tid + 256]);
}

// ---------------- LayerNorm: f32 in -> bf16 out ----------------
__global__ __launch_bounds__(256) void k_ln(const float* __restrict__ X,
                                            const float* __restrict__ g,
                                            const float* __restrict__ bb,
                                            bf16_t* __restrict__ XN){
  int tok = blockIdx.x;
  int tid = threadIdx.x;
  const float* xr = X + (long)tok * DIMC;
  float v0 = xr[tid], v1 = xr[tid + 256];
  float s = v0 + v1;
  float q = v0 * v0 + v1 * v1;
  s = wsum(s); q = wsum(q);
  __shared__ float r1[4], r2[4];
  if ((tid & 63) == 0){ r1[tid >> 6] = s; r2[tid >> 6] = q; }
  __syncthreads();
  float ts = r1[0] + r1[1] + r1[2] + r1[3];
  float tq = r2[0] + r2[1] + r2[2] + r2[3];
  float mean = ts * (1.0f / DIMC);
  float var  = tq * (1.0f / DIMC) - mean * mean;
  float rinv = rsqrtf(var + EPSF);
  XN[(long)tok * DIMC + tid]       = __float2bfloat16((v0 - mean) * rinv * g[tid]       + bb[tid]);
  XN[(long)tok * DIMC + tid + 256] = __float2bfloat16((v1 - mean) * rinv * g[tid + 256] + bb[tid + 256]);
}

// ---------------- bf16 MFMA GEMM: 64M x TN tile, BK k-chunk --------------------------
// Raising MFMA-per-barrier on the proven VALU-staged dbuf structure:
//  TN=128/BK=32 (QKVG, FF1): 8 MFMA + 6 ds_read per wave per barrier, LDS 30.7KB.
//  TN=64 /BK=64 (WO, FF2):   8 MFMA + 8 ds_read per wave per barrier, half the barriers.
// Grid = ntiles*104 (13 m-groups x 8 XCD), guard mt<98. B rows clamped for ragged N.
// VTo != nullptr (QKVG GEMM only): also write V columns (ncol in [1024,1536))
// transposed to VTo[b*512 + d][tok] (bf16, row width 800; cols 784..799 pre-zeroed).
template<int OUTBF, int ACT, int TN, int BK>
__global__ __launch_bounds__(256) void k_mgemm(const bf16_t* __restrict__ A,
                                               const bf16_t* __restrict__ Bm,
                                               float* Cf,
                                               bf16_t* Cb,
                                               const float* __restrict__ bias,
                                               const float* res,
                                               int M, int N, int K, int ldc, int ccol,
                                               bf16_t* VTo){
  constexpr int NTW = TN / 2;              // wave n-extent
  constexpr int NF  = TN / 32;             // n-frags per wave (2 or 4)
  constexpr int KS  = BK / 32;             // k-steps per chunk (1 or 2)
  constexpr int AVN = (64 * BK) / 2048;    // per-thread A stage vecs (1 or 2)
  constexpr int BVN = (TN * BK) / 2048;    // per-thread B stage vecs (2)
  constexpr int RPB = BK / 8;              // 16B vecs per row
  constexpr int RST = 256 / RPB;           // row stride between a thread's vecs

  int id = blockIdx.x;
  int xcd = id & 7;
  int j = id >> 3;
  int nt = j / 13;
  int mt = xcd * 13 + (j - nt * 13);
  if (mt >= MT_) return;
  int bm = mt * 64, bn = nt * TN;

  __shared__ bf16_t As[2][64][BK + 8];
  __shared__ bf16_t Bs[2][TN][BK + 8];
  int tid = threadIdx.x;
  int w = tid >> 6, lane = tid & 63;
  int wm = (w & 1) * 32, wn = (w >> 1) * NTW;
  int quad = lane >> 4, l16 = lane & 15;

  int vrow = tid / RPB;
  int vcol = (tid % RPB) * 8;
  const bf16_t* ap[AVN];
  const bf16_t* bp[BVN];
#pragma unroll
  for (int i = 0; i < AVN; i++)
    ap[i] = A + (long)(bm + vrow + i * RST) * K + vcol;
#pragma unroll
  for (int i = 0; i < BVN; i++){
    int r = bn + vrow + i * RST;
    if (r >= N) r = N - 1;
    bp[i] = Bm + (long)r * K + vcol;
  }

  floatx4 acc[2][NF];
#pragma unroll
  for (int i = 0; i < 2; i++)
#pragma unroll
    for (int jj = 0; jj < NF; jj++) acc[i][jj] = (floatx4)(0.0f);

  uintx4 aR[AVN], bR[BVN];
#pragma unroll
  for (int i = 0; i < AVN; i++) aR[i] = *(const uintx4*)ap[i];
#pragma unroll
  for (int i = 0; i < BVN; i++) bR[i] = *(const uintx4*)bp[i];

  int nch = K / BK;
  for (int ch = 0; ch < nch; ch++){
    int buf = ch & 1;
#pragma unroll
    for (int i = 0; i < AVN; i++) *(uintx4*)&As[buf][vrow + i * RST][vcol] = aR[i];
#pragma unroll
    for (int i = 0; i < BVN; i++) *(uintx4*)&Bs[buf][vrow + i * RST][vcol] = bR[i];
    __syncthreads();
    if (ch + 1 < nch){
      int ko = (ch + 1) * BK;
#pragma unroll
      for (int i = 0; i < AVN; i++) aR[i] = *(const uintx4*)(ap[i] + ko);
#pragma unroll
      for (int i = 0; i < BVN; i++) bR[i] = *(const uintx4*)(bp[i] + ko);
    }
#pragma unroll
    for (int ks = 0; ks < KS; ks++){
      bf16x8 a0 = *(bf16x8*)&As[buf][wm + l16][ks * 32 + quad * 8];
      bf16x8 a1 = *(bf16x8*)&As[buf][wm + 16 + l16][ks * 32 + quad * 8];
      bf16x8 bf[NF];
#pragma unroll
      for (int f = 0; f < NF; f++)
        bf[f] = *(bf16x8*)&Bs[buf][wn + f * 16 + l16][ks * 32 + quad * 8];
#pragma unroll
      for (int f = 0; f < NF; f++){
        acc[0][f] = __builtin_amdgcn_mfma_f32_16x16x32_bf16(a0, bf[f], acc[0][f], 0, 0, 0);
        acc[1][f] = __builtin_amdgcn_mfma_f32_16x16x32_bf16(a1, bf[f], acc[1][f], 0, 0, 0);
      }
    }
    // no trailing barrier: next iter writes the other buffer; re-write of this
    // buffer happens only after the next barrier, which is after all reads here.
  }
#pragma unroll
  for (int tm = 0; tm < 2; tm++){
#pragma unroll
    for (int tn = 0; tn < NF; tn++){
      int ncol = bn + wn + tn * 16 + l16;
      if (ncol >= N) continue;
#pragma unroll
      for (int reg = 0; reg < 4; reg++){
        long mrow = bm + wm + tm * 16 + quad * 4 + reg;
        float v = acc[tm][tn][reg];
        if (bias) v += bias[ncol];
        if (ACT == 1) v = geluf(v);
        long off = mrow * (long)ldc + ccol + ncol;
        if (res) v += res[off];
        if (OUTBF){
          Cb[off] = __float2bfloat16(v);
          if (VTo && ncol >= 1024 && ncol < 1536){
            int bb2 = (int)(mrow / SEQ_);
            int tok = (int)(mrow - (long)bb2 * SEQ_);
            VTo[((long)(bb2 * 512 + (ncol - 1024))) * 800 + tok] = __float2bfloat16(v);
          }
        }
        else       Cf[off] = v;
      }
    }
  }
}

// ---------------- compressed-block mean pooling, vectorized + coalesced -------------
__global__ __launch_bounds__(512) void k_cpool(const bf16_t* __restrict__ qkvg,
                                               float* __restrict__ ck,
                                               float* __restrict__ cv){
  int bj = blockIdx.x;
  int j = bj % NC_;
  int b = bj / NC_;
  int tid = threadIdx.x;
  int seg = tid & 127;
  int rg  = tid >> 7;
  __shared__ float part[4][1024];
  const bf16_t* base = qkvg + ((long)b * SEQ_ + (long)j * CST_) * QLD + 512;
  float acc[8] = {0.f,0.f,0.f,0.f,0.f,0.f,0.f,0.f};
  for (int r = rg; r < CBS_; r += 4){
    uintx4 v = *(const uintx4*)(base + (long)r * QLD + seg * 8);
    bf16_t tmp[8]; *(uintx4*)tmp = v;
#pragma unroll
    for (int q = 0; q < 8; q++) acc[q] += __bfloat162float(tmp[q]);
  }
#pragma unroll
  for (int q = 0; q < 8; q++) part[rg][seg * 8 + q] = acc[q];
  __syncthreads();
  for (int c = tid; c < 1024; c += 512){
    float s = (part[0][c] + part[1][c]) + (part[2][c] + part[3][c]);
    s *= (1.0f / CBS_);
    if (c < 512) ck[bj * DIMC + c] = s;
    else         cv[bj * DIMC + (c - 512)] = s;
  }
}

// ---------------- fused NSA attention v7 (unchanged this round) ---------------------
__global__ __launch_bounds__(256) void k_attn(const bf16_t* __restrict__ qkvg,
                                              const float* __restrict__ ck,
                                              const float* __restrict__ cv,
                                              const bf16_t* __restrict__ vtg,
                                              bf16_t* __restrict__ oattn){
  int tid = threadIdx.x;
  int w = tid >> 6, lane = tid & 63;
  int quad = lane >> 4, l16 = lane & 15;
  int id = blockIdx.x;
  int xcd = id & 7;
  int j = id >> 3;               // 0..223
  int bh = xcd * 8 + (j / 28);   // all 28 tiles of a bh on one XCD
  int i0 = (j % 28) * TQ_;
  int h = bh & 7, b = bh >> 3;
  const float scale = 0.125f;

  __shared__ __align__(16) char smem[77040];
  bf16_t (*Qs)[72]    = (bf16_t(*)[72])(smem);             // 4608 B (rows 28-31 zero)
  bf16_t (*Ks0)[72]   = (bf16_t(*)[72])(smem + 4608);      // 9216 B (dbuf 0, 64 keys)
  bf16_t (*Ks1)[72]   = (bf16_t(*)[72])(smem + 13824);     // 9216 B (dbuf 1)
  bf16_t (*sbuf)[808] = (bf16_t(*)[808])(smem + 23040);    // 45248 B
  float  (*outc_s)[64]= (float(*)[64])(smem + 68288);      // 7168 B (absorbs overreads)
  int*   sel_s = (int*)(smem + 75456);                     // 112 B
  float* cw_s  = (float*)(smem + 75568);                   // 112 B
  float* cs_s  = (float*)(smem + 75680);                   // 112 B
  float* g1_s  = (float*)(smem + 75792);                   // 112 B
  float* g2_s  = (float*)(smem + 75904);                   // 112 B
  float (*red_s)[4][16] = (float(*)[4][16])(smem + 76016); // 1024 B

  const long rowBase = (long)b * SEQ_ * QLD + h * 64;     // + token*QLD + {0,512,1024}

  // ---- Phase A: stage Q tile (28 rows) + zero rows 28-31 ----
  if (tid < 224){
    int q = tid >> 3, seg = tid & 7;
    uintx4 qv = *(const uintx4*)(qkvg + rowBase + (long)(i0 + q) * QLD + seg * 8);
    *(uintx4*)&Qs[q][seg * 8] = qv;
  } else {
    int u = tid - 224;
    int r = 28 + (u >> 3), seg = u & 7;
    *(uintx4*)&Qs[r][seg * 8] = (uintx4){0u, 0u, 0u, 0u};
  }
  __syncthreads();

  // ---- prefetch K chunk 0 (latency hidden under Phase B) ----
  int r0i = tid >> 3, s0i = tid & 7;
  int r1i = 32 + r0i;
  uintx4 kreg0 = *(const uintx4*)(qkvg + rowBase + (long)r0i * QLD + 512 + s0i * 8);
  uintx4 kreg1 = *(const uintx4*)(qkvg + rowBase + (long)r1i * QLD + 512 + s0i * 8);

  // ---- Phase B: compressed branch + gates + top-1 selection ----
  {
    const float* CKp = ck + (long)b * NC_ * DIMC + h * 64 + lane;
    const float* CVp = cv + (long)b * NC_ * DIMC + h * 64 + lane;
    float k0 = CKp[0], k1 = CKp[512], k2 = CKp[1024];
    float v0 = CVp[0], v1 = CVp[512], v2 = CVp[1024];
#pragma unroll
    for (int qp = 0; qp < 7; qp++){
      int qg = w * 7 + qp;
      float qd = __bfloat162float(Qs[qg][lane]);
      float s0 = wsum(qd * k0) * scale;
      float s1 = wsum(qd * k1) * scale;
      float s2 = wsum(qd * k2) * scale;
      float m3 = fmaxf(s0, fmaxf(s1, s2));
      float e0 = __expf(s0 - m3), e1 = __expf(s1 - m3), e2 = __expf(s2 - m3);
      float inv = 1.0f / (e0 + e1 + e2);
      const bf16_t* grow = qkvg + (long)(b * SEQ_ + i0 + qg) * QLD + 1536 + h * 3;
      float g0 = sigmoidf_(__bfloat162float(grow[0]));
      float g1v = sigmoidf_(__bfloat162float(grow[1]));
      float g2v = sigmoidf_(__bfloat162float(grow[2]));
      outc_s[qg][lane] = g0 * (e0 * v0 + e1 * v1 + e2 * v2) * inv;
      int selv = (s2 > s0) ? 1 : 0;   // imp1>imp0 <=> p2>p0 <=> s2>s0
      if (lane == 0){ sel_s[qg] = selv; g1_s[qg] = g1v; g2_s[qg] = g2v; }
    }
  }

  // hoist Q B-fragments (chunk-invariant)
  bf16x8 a00 = *(bf16x8*)&Qs[l16][quad * 8];
  bf16x8 a01 = *(bf16x8*)&Qs[l16][32 + quad * 8];
  bf16x8 a10 = *(bf16x8*)&Qs[16 + l16][quad * 8];
  bf16x8 a11 = *(bf16x8*)&Qs[16 + l16][32 + quad * 8];

  __syncthreads();   // sel_s/g1_s/g2_s/outc_s visible to all waves

  // ---- Phase C: S^T = K.Q^T via MFMA (13 chunks of 64 keys, dbuf) ----------------
  int sel0i = sel_s[l16];
  int sel1i = (l16 < 12) ? sel_s[16 + l16] : 0;
  bool sv0 = (sel0i != 0), sv1 = (sel1i != 0);
  int iq0 = i0 + l16, iq1 = i0 + 16 + l16;
  float sw0 = 0.f, ss0 = 0.f, sw1 = 0.f, ss1 = 0.f;

  for (int ch = 0; ch < 13; ch++){
    bf16_t (*Kb)[72] = (ch & 1) ? Ks1 : Ks0;
    *(uintx4*)&Kb[r0i][s0i * 8] = kreg0;
    *(uintx4*)&Kb[r1i][s0i * 8] = kreg1;
    __syncthreads();
    if (ch + 1 < 13){
      int c0n = (ch + 1) * 64;
      int t0 = c0n + r0i; if (t0 > 783) t0 = 783;
      int t1 = c0n + r1i; if (t1 > 783) t1 = 783;
      kreg0 = *(const uintx4*)(qkvg + rowBase + (long)t0 * QLD + 512 + s0i * 8);
      kreg1 = *(const uintx4*)(qkvg + rowBase + (long)t1 * QLD + 512 + s0i * 8);
    }
    bf16x8 k0 = *(bf16x8*)&Kb[w * 16 + l16][quad * 8];
    bf16x8 k1 = *(bf16x8*)&Kb[w * 16 + l16][32 + quad * 8];
    floatx4 d0 = (floatx4)(0.0f), d1 = (floatx4)(0.0f);
    d0 = __builtin_amdgcn_mfma_f32_16x16x32_bf16(k0, a00, d0, 0, 0, 0);
    d0 = __builtin_amdgcn_mfma_f32_16x16x32_bf16(k1, a01, d0, 0, 0, 0);
    d1 = __builtin_amdgcn_mfma_f32_16x16x32_bf16(k0, a10, d1, 0, 0, 0);
    d1 = __builtin_amdgcn_mfma_f32_16x16x32_bf16(k1, a11, d1, 0, 0, 0);
    int kb = ch * 64 + w * 16 + quad * 4;
    union { bf16_t hh[4]; uintx2 v; } p0, p1;
#pragma unroll
    for (int r = 0; r < 4; r++){
      int key = kb + r;
      float ex0 = __expf(d0[r] * scale);
      float ex1 = __expf(d1[r] * scale);
      bool valid = key < 784;
      if (valid && key >= iq0 - 195 && key <= iq0 + 195) sw0 += ex0;
      if (valid && ((key >= 392) == sv0))                ss0 += ex0;
      if (valid && key >= iq1 - 195 && key <= iq1 + 195) sw1 += ex1;
      if (valid && ((key >= 392) == sv1))                ss1 += ex1;
      p0.hh[r] = __float2bfloat16(ex0);
      p1.hh[r] = __float2bfloat16(ex1);
    }
    if (kb < 784){
      *(uintx2*)&sbuf[l16][kb] = p0.v;
      if (l16 < 12) *(uintx2*)&sbuf[16 + l16][kb] = p1.v;
    }
  }

  // ---- combine row sums: quads via shfl, waves via 1KB LDS ----
  sw0 += __shfl_xor(sw0, 16, 64); sw0 += __shfl_xor(sw0, 32, 64);
  ss0 += __shfl_xor(ss0, 16, 64); ss0 += __shfl_xor(ss0, 32, 64);
  sw1 += __shfl_xor(sw1, 16, 64); sw1 += __shfl_xor(sw1, 32, 64);
  ss1 += __shfl_xor(ss1, 16, 64); ss1 += __shfl_xor(ss1, 32, 64);
  if (quad == 0){
    red_s[w][0][l16] = sw0; red_s[w][1][l16] = ss0;
    red_s[w][2][l16] = sw1; red_s[w][3][l16] = ss1;
  }
  __syncthreads();
  if (tid < 28){
    int q = tid, t = q >> 4, l = q & 15;
    float sw = 0.f, ss = 0.f;
#pragma unroll
    for (int wv = 0; wv < 4; wv++){ sw += red_s[wv][2 * t][l]; ss += red_s[wv][2 * t + 1][l]; }
    cw_s[q] = g2_s[q] / sw;
    cs_s[q] = g1_s[q] / ss;
  }
  __syncthreads();

  // ---- prefetch first V fragment (hidden under build-W) ----
  const bf16_t* vrow = vtg + ((long)(b * 512 + h * 64 + w * 16 + l16)) * 800 + quad * 8;
  bf16x8 bv = *(const bf16x8*)vrow;

  // ---- build combined weight matrix W in place (b128; zero cols 784..799) ----
  for (int t = tid; t < 2800; t += 256){
    int q = t / 100;
    int c0 = (t - q * 100) * 8;
    uintx4 ov;
    if (c0 >= 784){
      ov = (uintx4){0u, 0u, 0u, 0u};
    } else {
      union { bf16_t hh[8]; uintx4 v; } in, out;
      in.v = *(uintx4*)&sbuf[q][c0];
      int iq = i0 + q;
      float cwv = cw_s[q], csv = cs_s[q];
      float cse = ((c0 >= 392) == (sel_s[q] != 0)) ? csv : 0.0f;
#pragma unroll
      for (int jj = 0; jj < 8; jj++){
        int c = c0 + jj;
        float coef = cse;
        if (c >= iq - 195 && c <= iq + 195) coef += cwv;
        out.hh[jj] = __float2bfloat16(__bfloat162float(in.hh[jj]) * coef);
      }
      ov = out.v;
    }
    *(uintx4*)&sbuf[q][c0] = ov;
  }
  __syncthreads();

  // ---- Phase D: out = W . V via MFMA, V fragments straight from global VT --------
  floatx4 o0 = (floatx4)(0.0f), o1 = (floatx4)(0.0f);
#pragma unroll 5
  for (int st = 0; st < 25; st++){
    bf16x8 bcur = bv;
    if (st + 1 < 25) bv = *(const bf16x8*)(vrow + (st + 1) * 32);
    int kc = st * 32 + quad * 8;
    bf16x8 av0 = *(bf16x8*)&sbuf[l16][kc];
    bf16x8 av1 = *(bf16x8*)&sbuf[16 + l16][kc];
    o0 = __builtin_amdgcn_mfma_f32_16x16x32_bf16(av0, bcur, o0, 0, 0, 0);
    o1 = __builtin_amdgcn_mfma_f32_16x16x32_bf16(av1, bcur, o1, 0, 0, 0);
  }

  // ---- epilogue: add compressed branch, write bf16 ----
  int d = w * 16 + l16;
#pragma unroll
  for (int reg = 0; reg < 4; reg++){
    int q = quad * 4 + reg;
    float o = o0[reg] + outc_s[q][d];
    oattn[((long)(b * SEQ_ + i0 + q)) * DIMC + h * 64 + d] = __float2bfloat16(o);
    int q2 = q + 16;
    if (q2 < 28){
      float o2 = o1[reg] + outc_s[q2][d];
      oattn[((long)(b * SEQ_ + i0 + q2)) * DIMC + h * 64 + d] = __float2bfloat16(o2);
    }
  }
}

// ---------------- host launcher ----------------
extern "C" void kernel_launch(void* const* d_in, const int* in_sizes, int n_in,
                              void* d_out, int out_size, void* d_ws, size_t ws_size,
                              hipStream_t stream){
  const float* xin  = (const float*)d_in[0];
  const float* pos  = (const float*)d_in[1];
  const float* angm = (const float*)d_in[2];
  const float* Wq   = (const float*)d_in[3];
  const float* Wk   = (const float*)d_in[4];
  const float* Wv   = (const float*)d_in[5];
  const float* Wo   = (const float*)d_in[6];
  const float* Wg   = (const float*)d_in[7];
  const float* fng  = (const float*)d_in[8];
  const float* fnb  = (const float*)d_in[9];
  const float* fw1  = (const float*)d_in[10];
  const float* fb1  = (const float*)d_in[11];
  const float* fw2  = (const float*)d_in[12];
  const float* fb2  = (const float*)d_in[13];

  // workspace layout: ~70.7 MB total (BUFb/H1b share one region — disjoint live ranges)
  char* cw = (char*)d_ws;
  float* X = (float*)cw;             cw += (long)NTOK * 512 * 4;     // 12.85 MB
  bf16_t* XRb = (bf16_t*)cw;         cw += (long)NTOK * 512 * 2;     //  6.42 MB
  bf16_t* OAb = (bf16_t*)cw;         cw += (long)NTOK * 512 * 2;     //  6.42 MB
  bf16_t* SH  = (bf16_t*)cw;         cw += (long)NTOK * FF_ * 2;     // 25.69 MB (BUFb/H1b)
  float* CK = (float*)cw;            cw += (long)B_ * NC_ * DIMC * 4;
  float* CV = (float*)cw;            cw += (long)B_ * NC_ * DIMC * 4;
  bf16_t* Wqkvgb = (bf16_t*)cw;      cw += (long)2 * QLD * 512 * 2;  //  3.19 MB
  bf16_t* WOb    = (bf16_t*)cw;      cw += (long)2 * 512 * 512 * 2;  //  1.05 MB
  bf16_t* FW1b   = (bf16_t*)cw;      cw += (long)2 * FF_ * 512 * 2;  //  4.19 MB
  bf16_t* FW2b   = (bf16_t*)cw;      cw += (long)2 * 512 * FF_ * 2;  //  4.19 MB
  bf16_t* VTb    = (bf16_t*)cw;      cw += (long)B_ * 512 * 800 * 2; //  6.55 MB
  bf16_t* BUFb = SH;   // [NTOK, QLD]  (QKVG output; dies after k_attn)
  bf16_t* H1b  = SH;   // [NTOK, FF_]  (FF1 output; born after k_ln)

  // per-call weight conversion (deterministic, same work every call)
  k_wconv1<<<(2 * QLD * 512) / 256, 256, 0, stream>>>(Wq, Wk, Wv, Wg, Wqkvgb);
  k_wconv2<<<(2 * 512 * 512) / 256, 256, 0, stream>>>(Wo, WOb);
  k_cast<<<(2 * FF_ * 512) / 256, 256, 0, stream>>>(fw1, FW1b);
  k_cast<<<(2 * 512 * FF_) / 256, 256, 0, stream>>>(fw2, FW2b);

  // zero VT once: tokens 784..799 stay zero; cols 0..783 rewritten each layer
  k_zero<<<1600, 256, 0, stream>>>((uintx4*)VTb);   // 6,553,600 B

  k_init<<<12544, 256, 0, stream>>>(xin, pos, X);

  for (int l = 0; l < 2; l++){
    k_rms<<<NTOK, 256, 0, stream>>>(X, angm + (long)l * DIMC, XRb);

    // fused QKV+G GEMM: [6272,512] x [1560,512]^T -> BUFb [6272,1560] bf16 (+ VT)
    // TN=128: 13 n-tiles (last ragged, clamped)
    k_mgemm<1, 0, 128, 32><<<13 * 104, 256, 0, stream>>>(
        XRb, Wqkvgb + (long)l * QLD * 512, nullptr, BUFb, nullptr, nullptr,
        NTOK, QLD, 512, QLD, 0, VTb);

    k_cpool<<<B_ * NC_, 512, 0, stream>>>(BUFb, CK, CV);

    k_attn<<<8 * 8 * 28, 256, 0, stream>>>(BUFb, CK, CV, VTb, OAb);

    // Wo GEMM: f32 out + residual into X (TN=64, BK=64: half the barriers)
    k_mgemm<0, 0, 64, 64><<<8 * 104, 256, 0, stream>>>(
        OAb, WOb + (long)l * 512 * 512, X, nullptr, nullptr, X,
        NTOK, 512, 512, 512, 0, nullptr);

    k_ln<<<NTOK, 256, 0, stream>>>(X, fng + (long)l * DIMC, fnb + (long)l * DIMC, XRb);

    // FF1 + GELU, bf16 out into H1b (TN=128)
    k_mgemm<1, 1, 128, 32><<<16 * 104, 256, 0, stream>>>(
        XRb, FW1b + (long)l * FF_ * 512, nullptr, H1b, fb1 + (long)l * FF_, nullptr,
        NTOK, FF_, 512, FF_, 0, nullptr);
    // FF2, f32 out + residual into X (TN=64, BK=64)
    k_mgemm<0, 0, 64, 64><<<8 * 104, 256, 0, stream>>>(
        H1b, FW2b + (long)l * 512 * FF_, X, nullptr, fb2 + (long)l * DIMC, X,
        NTOK, 512, FF_, 512, 0, nullptr);
  }

  k_final<<<12544, 256, 0, stream>>>(X, (float*)d_out);
}

// Round 5
// 575.348 us; speedup vs baseline: 1.3622x; 1.1317x over previous
//
#include <hip/hip_runtime.h>
#include <hip/hip_bf16.h>
#include <math.h>

// ---- static config (matches reference) ----
#define B_      8
#define DIMC    512
#define SEQ_    784
#define HEADS_  8
#define DH_     64
#define NTOK    (B_*SEQ_)      // 6272
#define QLD     1560           // q(512) | k(512) | v(512) | gates(24)
#define WIN_    196
#define CBS_    392
#define CST_    196
#define NC_     3
#define EPSF    1e-5f
#define FF_     2048
#define TQ_     28             // queries per block (28*28 = 784)
#define MT_     98             // m-tiles (6272/64)

typedef __hip_bfloat16 bf16_t;
typedef __attribute__((ext_vector_type(8))) short bf16x8;
typedef __attribute__((ext_vector_type(4))) float floatx4;
typedef __attribute__((ext_vector_type(4))) unsigned int uintx4;
typedef __attribute__((ext_vector_type(2))) unsigned int uintx2;

// ---------------- helpers ----------------
__device__ __forceinline__ float wsum(float x){
#pragma unroll
  for (int o = 32; o; o >>= 1) x += __shfl_xor(x, o, 64);
  return x;
}
__device__ __forceinline__ float geluf(float x){
  return 0.5f * x * (1.0f + erff(x * 0.70710678118654752f));
}
__device__ __forceinline__ float sigmoidf_(float x){
  return 1.0f / (1.0f + __expf(-x));
}

// ---------------- init (tiled transpose): x[b,c,h,w] f32 -> X[b,p,c] f32 + pos ------
__global__ __launch_bounds__(256) void k_init(const float* __restrict__ xin,
                                              const float* __restrict__ pos,
                                              float* __restrict__ X){
  __shared__ float tl[32][33];
  int blk = blockIdx.x;              // 8 * 25 * 16
  int ct = blk & 15;
  int pt = (blk >> 4) % 25;
  int b  = blk / (16 * 25);
  int p0 = pt * 32, c0 = ct * 32;
  int tx = threadIdx.x & 31, ty = threadIdx.x >> 5;
#pragma unroll
  for (int i = 0; i < 4; i++){
    int p = p0 + tx;
    if (p < SEQ_) tl[ty + i * 8][tx] = xin[((long)(b * DIMC + c0 + ty + i * 8)) * SEQ_ + p];
  }
  __syncthreads();
#pragma unroll
  for (int i = 0; i < 4; i++){
    int p = p0 + ty + i * 8;
    if (p < SEQ_)
      X[((long)(b * SEQ_ + p)) * DIMC + c0 + tx] = tl[tx][ty + i * 8] + pos[p];
  }
}

// ---------------- final (tiled transpose): X[b,p,c] -> out[b,c,h,w] f32 -------------
__global__ __launch_bounds__(256) void k_final(const float* __restrict__ X,
                                               float* __restrict__ out){
  __shared__ float tl[32][33];
  int blk = blockIdx.x;              // 8 * 25 * 16
  int ct = blk & 15;
  int pt = (blk >> 4) % 25;
  int b  = blk / (16 * 25);
  int p0 = pt * 32, c0 = ct * 32;
  int tx = threadIdx.x & 31, ty = threadIdx.x >> 5;
#pragma unroll
  for (int i = 0; i < 4; i++){
    int p = p0 + ty + i * 8;
    if (p < SEQ_) tl[ty + i * 8][tx] = X[((long)(b * SEQ_ + p)) * DIMC + c0 + tx];
  }
  __syncthreads();
#pragma unroll
  for (int i = 0; i < 4; i++){
    int p = p0 + tx;
    if (p < SEQ_)
      out[((long)(b * DIMC + c0 + ty + i * 8)) * SEQ_ + p] = tl[tx][ty + i * 8];
  }
}

// ---------------- weight conversion (tiled): WQKVG [l][n][k] bf16 -------------------
__global__ __launch_bounds__(256) void k_wconv1(const float* __restrict__ Wq,
                                                const float* __restrict__ Wk,
                                                const float* __restrict__ Wv,
                                                const float* __restrict__ Wg,
                                                bf16_t* __restrict__ Wb){
  __shared__ float tl[32][33];
  int blk = blockIdx.x;              // 2 * 49 * 16
  int kt = blk & 15;
  int ntf = (blk >> 4) % 49;
  int l = blk / (16 * 49);
  int n0 = ntf * 32, k0 = kt * 32;
  int tx = threadIdx.x & 31, ty = threadIdx.x >> 5;
#pragma unroll
  for (int i = 0; i < 4; i++){
    int n = n0 + tx, k = k0 + ty + i * 8;
    float v = 0.0f;
    if (n < 1536){
      int which = n >> 9, nn = n & 511;
      const float* W = (which == 0) ? Wq : ((which == 1) ? Wk : Wv);
      v = W[((long)(l * 512 + k)) * 512 + nn];
    } else if (n < QLD){
      v = Wg[((long)(l * 512 + k)) * 24 + (n - 1536)];
    }
    tl[ty + i * 8][tx] = v;
  }
  __syncthreads();
#pragma unroll
  for (int i = 0; i < 4; i++){
    int n = n0 + ty + i * 8, k = k0 + tx;
    if (n < QLD)
      Wb[((long)(l * QLD + n)) * 512 + k] = __float2bfloat16(tl[tx][ty + i * 8]);
  }
}

// ---------------- WO transpose (tiled): Wb[l][n][k] = Wo[l][k][n] -------------------
__global__ __launch_bounds__(256) void k_wconv2(const float* __restrict__ Wo,
                                                bf16_t* __restrict__ Wb){
  __shared__ float tl[32][33];
  int blk = blockIdx.x;              // 2 * 16 * 16
  int kt = blk & 15;
  int ntf = (blk >> 4) & 15;
  int l = blk >> 8;
  int n0 = ntf * 32, k0 = kt * 32;
  int tx = threadIdx.x & 31, ty = threadIdx.x >> 5;
#pragma unroll
  for (int i = 0; i < 4; i++)
    tl[ty + i * 8][tx] = Wo[((long)(l * 512 + k0 + ty + i * 8)) * 512 + n0 + tx];
  __syncthreads();
#pragma unroll
  for (int i = 0; i < 4; i++)
    Wb[((long)(l * 512 + n0 + ty + i * 8)) * 512 + k0 + tx] = __float2bfloat16(tl[tx][ty + i * 8]);
}

// ---------------- plain f32 -> bf16 cast ----------------
__global__ __launch_bounds__(256) void k_cast(const float* __restrict__ src,
                                              bf16_t* __restrict__ dst){
  int idx = blockIdx.x * 256 + threadIdx.x;
  dst[idx] = __float2bfloat16(src[idx]);
}

// ---------------- 16B-granular zero fill ----------------
__global__ __launch_bounds__(256) void k_zero(uintx4* __restrict__ p){
  p[blockIdx.x * 256 + threadIdx.x] = (uintx4){0u, 0u, 0u, 0u};
}

// ---------------- RMSNorm: f32 in -> bf16 out ----------------
__global__ __launch_bounds__(256) void k_rms(const float* __restrict__ X,
                                             const float* __restrict__ g,
                                             bf16_t* __restrict__ XR){
  int tok = blockIdx.x;
  int tid = threadIdx.x;
  const float* xr = X + (long)tok * DIMC;
  float v0 = xr[tid], v1 = xr[tid + 256];
  float ss = v0 * v0 + v1 * v1;
  ss = wsum(ss);
  __shared__ float red[4];
  if ((tid & 63) == 0) red[tid >> 6] = ss;
  __syncthreads();
  float tot = red[0] + red[1] + red[2] + red[3];
  float r = rsqrtf(tot * (1.0f / DIMC) + EPSF);
  XR[(long)tok * DIMC + tid]       = __float2bfloat16(v0 * r * g[tid]);
  XR[(long)tok * DIMC + tid + 256] = __float2bfloat16(v1 * r * g[tid + 256]);
}

// ---------------- LayerNorm: f32 in -> bf16 out ----------------
__global__ __launch_bounds__(256) void k_ln(const float* __restrict__ X,
                                            const float* __restrict__ g,
                                            const float* __restrict__ bb,
                                            bf16_t* __restrict__ XN){
  int tok = blockIdx.x;
  int tid = threadIdx.x;
  const float* xr = X + (long)tok * DIMC;
  float v0 = xr[tid], v1 = xr[tid + 256];
  float s = v0 + v1;
  float q = v0 * v0 + v1 * v1;
  s = wsum(s); q = wsum(q);
  __shared__ float r1[4], r2[4];
  if ((tid & 63) == 0){ r1[tid >> 6] = s; r2[tid >> 6] = q; }
  __syncthreads();
  float ts = r1[0] + r1[1] + r1[2] + r1[3];
  float tq = r2[0] + r2[1] + r2[2] + r2[3];
  float mean = ts * (1.0f / DIMC);
  float var  = tq * (1.0f / DIMC) - mean * mean;
  float rinv = rsqrtf(var + EPSF);
  XN[(long)tok * DIMC + tid]       = __float2bfloat16((v0 - mean) * rinv * g[tid]       + bb[tid]);
  XN[(long)tok * DIMC + tid + 256] = __float2bfloat16((v1 - mean) * rinv * g[tid + 256] + bb[tid + 256]);
}

// ---------------- bf16 MFMA GEMM: 64M x TN tile, BK k-chunk (unchanged R4) ----------
template<int OUTBF, int ACT, int TN, int BK>
__global__ __launch_bounds__(256) void k_mgemm(const bf16_t* __restrict__ A,
                                               const bf16_t* __restrict__ Bm,
                                               float* Cf,
                                               bf16_t* Cb,
                                               const float* __restrict__ bias,
                                               const float* res,
                                               int M, int N, int K, int ldc, int ccol,
                                               bf16_t* VTo){
  constexpr int NTW = TN / 2;
  constexpr int NF  = TN / 32;
  constexpr int KS  = BK / 32;
  constexpr int AVN = (64 * BK) / 2048;
  constexpr int BVN = (TN * BK) / 2048;
  constexpr int RPB = BK / 8;
  constexpr int RST = 256 / RPB;

  int id = blockIdx.x;
  int xcd = id & 7;
  int j = id >> 3;
  int nt = j / 13;
  int mt = xcd * 13 + (j - nt * 13);
  if (mt >= MT_) return;
  int bm = mt * 64, bn = nt * TN;

  __shared__ bf16_t As[2][64][BK + 8];
  __shared__ bf16_t Bs[2][TN][BK + 8];
  int tid = threadIdx.x;
  int w = tid >> 6, lane = tid & 63;
  int wm = (w & 1) * 32, wn = (w >> 1) * NTW;
  int quad = lane >> 4, l16 = lane & 15;

  int vrow = tid / RPB;
  int vcol = (tid % RPB) * 8;
  const bf16_t* ap[AVN];
  const bf16_t* bp[BVN];
#pragma unroll
  for (int i = 0; i < AVN; i++)
    ap[i] = A + (long)(bm + vrow + i * RST) * K + vcol;
#pragma unroll
  for (int i = 0; i < BVN; i++){
    int r = bn + vrow + i * RST;
    if (r >= N) r = N - 1;
    bp[i] = Bm + (long)r * K + vcol;
  }

  floatx4 acc[2][NF];
#pragma unroll
  for (int i = 0; i < 2; i++)
#pragma unroll
    for (int jj = 0; jj < NF; jj++) acc[i][jj] = (floatx4)(0.0f);

  uintx4 aR[AVN], bR[BVN];
#pragma unroll
  for (int i = 0; i < AVN; i++) aR[i] = *(const uintx4*)ap[i];
#pragma unroll
  for (int i = 0; i < BVN; i++) bR[i] = *(const uintx4*)bp[i];

  int nch = K / BK;
  for (int ch = 0; ch < nch; ch++){
    int buf = ch & 1;
#pragma unroll
    for (int i = 0; i < AVN; i++) *(uintx4*)&As[buf][vrow + i * RST][vcol] = aR[i];
#pragma unroll
    for (int i = 0; i < BVN; i++) *(uintx4*)&Bs[buf][vrow + i * RST][vcol] = bR[i];
    __syncthreads();
    if (ch + 1 < nch){
      int ko = (ch + 1) * BK;
#pragma unroll
      for (int i = 0; i < AVN; i++) aR[i] = *(const uintx4*)(ap[i] + ko);
#pragma unroll
      for (int i = 0; i < BVN; i++) bR[i] = *(const uintx4*)(bp[i] + ko);
    }
#pragma unroll
    for (int ks = 0; ks < KS; ks++){
      bf16x8 a0 = *(bf16x8*)&As[buf][wm + l16][ks * 32 + quad * 8];
      bf16x8 a1 = *(bf16x8*)&As[buf][wm + 16 + l16][ks * 32 + quad * 8];
      bf16x8 bf[NF];
#pragma unroll
      for (int f = 0; f < NF; f++)
        bf[f] = *(bf16x8*)&Bs[buf][wn + f * 16 + l16][ks * 32 + quad * 8];
#pragma unroll
      for (int f = 0; f < NF; f++){
        acc[0][f] = __builtin_amdgcn_mfma_f32_16x16x32_bf16(a0, bf[f], acc[0][f], 0, 0, 0);
        acc[1][f] = __builtin_amdgcn_mfma_f32_16x16x32_bf16(a1, bf[f], acc[1][f], 0, 0, 0);
      }
    }
  }
#pragma unroll
  for (int tm = 0; tm < 2; tm++){
#pragma unroll
    for (int tn = 0; tn < NF; tn++){
      int ncol = bn + wn + tn * 16 + l16;
      if (ncol >= N) continue;
#pragma unroll
      for (int reg = 0; reg < 4; reg++){
        long mrow = bm + wm + tm * 16 + quad * 4 + reg;
        float v = acc[tm][tn][reg];
        if (bias) v += bias[ncol];
        if (ACT == 1) v = geluf(v);
        long off = mrow * (long)ldc + ccol + ncol;
        if (res) v += res[off];
        if (OUTBF){
          Cb[off] = __float2bfloat16(v);
          if (VTo && ncol >= 1024 && ncol < 1536){
            int bb2 = (int)(mrow / SEQ_);
            int tok = (int)(mrow - (long)bb2 * SEQ_);
            VTo[((long)(bb2 * 512 + (ncol - 1024))) * 800 + tok] = __float2bfloat16(v);
          }
        }
        else       Cf[off] = v;
      }
    }
  }
}

// ---------------- compressed-block mean pooling, vectorized + coalesced -------------
__global__ __launch_bounds__(512) void k_cpool(const bf16_t* __restrict__ qkvg,
                                               float* __restrict__ ck,
                                               float* __restrict__ cv){
  int bj = blockIdx.x;
  int j = bj % NC_;
  int b = bj / NC_;
  int tid = threadIdx.x;
  int seg = tid & 127;
  int rg  = tid >> 7;
  __shared__ float part[4][1024];
  const bf16_t* base = qkvg + ((long)b * SEQ_ + (long)j * CST_) * QLD + 512;
  float acc[8] = {0.f,0.f,0.f,0.f,0.f,0.f,0.f,0.f};
  for (int r = rg; r < CBS_; r += 4){
    uintx4 v = *(const uintx4*)(base + (long)r * QLD + seg * 8);
    bf16_t tmp[8]; *(uintx4*)tmp = v;
#pragma unroll
    for (int q = 0; q < 8; q++) acc[q] += __bfloat162float(tmp[q]);
  }
#pragma unroll
  for (int q = 0; q < 8; q++) part[rg][seg * 8 + q] = acc[q];
  __syncthreads();
  for (int c = tid; c < 1024; c += 512){
    float s = (part[0][c] + part[1][c]) + (part[2][c] + part[3][c]);
    s *= (1.0f / CBS_);
    if (c < 512) ck[bj * DIMC + c] = s;
    else         cv[bj * DIMC + (c - 512)] = s;
  }
}

// ---------------- fused NSA attention v8: fused per-chunk PV, no sbuf ---------------
// out = cw(q)*SUM_win exp*V + cs(q)*SUM_sel exp*V: normalizers are per-q and applied
// AFTER the key sum, masks are known per (q,key) at QK^T time. Per chunk: QK^T ->
// exp -> masked W tiles (win/sel, dbuf) -> barrier -> PV MFMA with V^T fragments
// straight from global VT. Deletes sbuf (45KB), build-W and Phase D.
// LDS 50.2KB -> 3 blocks/CU (was 2).
__global__ __launch_bounds__(256) void k_attn(const bf16_t* __restrict__ qkvg,
                                              const float* __restrict__ ck,
                                              const float* __restrict__ cv,
                                              const bf16_t* __restrict__ vtg,
                                              bf16_t* __restrict__ oattn){
  int tid = threadIdx.x;
  int w = tid >> 6, lane = tid & 63;
  int quad = lane >> 4, l16 = lane & 15;
  int id = blockIdx.x;
  int xcd = id & 7;
  int j = id >> 3;               // 0..223
  int bh = xcd * 8 + (j / 28);   // all 28 tiles of a bh on one XCD
  int i0 = (j % 28) * TQ_;
  int h = bh & 7, b = bh >> 3;
  const float scale = 0.125f;

  __shared__ bf16_t Qs[32][72];          // rows 28-31 zero
  __shared__ bf16_t Ks[2][64][72];       // K dbuf
  __shared__ bf16_t Wcw[2][32][72];      // win-masked W dbuf (rows 28-31 zero)
  __shared__ bf16_t Wcs[2][32][72];      // sel-masked W dbuf (rows 28-31 zero)
  __shared__ float outc_s[28][64];
  __shared__ int   sel_s[28];
  __shared__ float cw_s[28], cs_s[28], g1_s[28], g2_s[28];
  __shared__ float red_s[4][4][16];

  const long rowBase = (long)b * SEQ_ * QLD + h * 64;     // + token*QLD + {0,512,1024}

  // ---- Phase A: stage Q tile (28 rows) + zero rows 28-31; zero Wc rows 28-31 ----
  if (tid < 224){
    int q = tid >> 3, seg = tid & 7;
    uintx4 qv = *(const uintx4*)(qkvg + rowBase + (long)(i0 + q) * QLD + seg * 8);
    *(uintx4*)&Qs[q][seg * 8] = qv;
  } else {
    int u = tid - 224;
    int r = 28 + (u >> 3), seg = u & 7;
    *(uintx4*)&Qs[r][seg * 8] = (uintx4){0u, 0u, 0u, 0u};
  }
  for (int t = tid; t < 2 * 4 * 72; t += 256){
    int bufi = t / (4 * 72);
    int r = 28 + (t / 72) % 4;
    int c = t % 72;
    Wcw[bufi][r][c] = __float2bfloat16(0.0f);
    Wcs[bufi][r][c] = __float2bfloat16(0.0f);
  }
  __syncthreads();

  // ---- prefetch K chunk 0 (latency hidden under Phase B) ----
  int r0i = tid >> 3, s0i = tid & 7;
  int r1i = 32 + r0i;
  uintx4 kreg0 = *(const uintx4*)(qkvg + rowBase + (long)r0i * QLD + 512 + s0i * 8);
  uintx4 kreg1 = *(const uintx4*)(qkvg + rowBase + (long)r1i * QLD + 512 + s0i * 8);

  // ---- Phase B: compressed branch + gates + top-1 selection ----
  {
    const float* CKp = ck + (long)b * NC_ * DIMC + h * 64 + lane;
    const float* CVp = cv + (long)b * NC_ * DIMC + h * 64 + lane;
    float k0 = CKp[0], k1 = CKp[512], k2 = CKp[1024];
    float v0 = CVp[0], v1 = CVp[512], v2 = CVp[1024];
#pragma unroll
    for (int qp = 0; qp < 7; qp++){
      int qg = w * 7 + qp;
      float qd = __bfloat162float(Qs[qg][lane]);
      float s0 = wsum(qd * k0) * scale;
      float s1 = wsum(qd * k1) * scale;
      float s2 = wsum(qd * k2) * scale;
      float m3 = fmaxf(s0, fmaxf(s1, s2));
      float e0 = __expf(s0 - m3), e1 = __expf(s1 - m3), e2 = __expf(s2 - m3);
      float inv = 1.0f / (e0 + e1 + e2);
      const bf16_t* grow = qkvg + (long)(b * SEQ_ + i0 + qg) * QLD + 1536 + h * 3;
      float g0 = sigmoidf_(__bfloat162float(grow[0]));
      float g1v = sigmoidf_(__bfloat162float(grow[1]));
      float g2v = sigmoidf_(__bfloat162float(grow[2]));
      outc_s[qg][lane] = g0 * (e0 * v0 + e1 * v1 + e2 * v2) * inv;
      int selv = (s2 > s0) ? 1 : 0;   // imp1>imp0 <=> p2>p0 <=> s2>s0
      if (lane == 0){ sel_s[qg] = selv; g1_s[qg] = g1v; g2_s[qg] = g2v; }
    }
  }

  // hoist Q B-fragments (chunk-invariant)
  bf16x8 a00 = *(bf16x8*)&Qs[l16][quad * 8];
  bf16x8 a01 = *(bf16x8*)&Qs[l16][32 + quad * 8];
  bf16x8 a10 = *(bf16x8*)&Qs[16 + l16][quad * 8];
  bf16x8 a11 = *(bf16x8*)&Qs[16 + l16][32 + quad * 8];

  __syncthreads();   // sel_s/g1_s/g2_s visible; Wc zero rows done

  // ---- main loop: 13 chunks of 64 keys, fused QK^T + masked-W + PV ----------------
  int sel0i = sel_s[l16];
  int sel1i = (l16 < 12) ? sel_s[16 + l16] : 0;
  bool sv0 = (sel0i != 0), sv1 = (sel1i != 0);
  int iq0 = i0 + l16, iq1 = i0 + 16 + l16;
  float sw0 = 0.f, ss0 = 0.f, sw1 = 0.f, ss1 = 0.f;

  const bf16_t* vbase = vtg + ((long)(b * 512 + h * 64 + w * 16 + l16)) * 800;
  floatx4 ow0 = (floatx4)(0.0f), ow1 = (floatx4)(0.0f);
  floatx4 os0 = (floatx4)(0.0f), os1 = (floatx4)(0.0f);

  for (int ch = 0; ch < 13; ch++){
    int buf = ch & 1;
    int K0 = ch * 64;
    // stage K chunk
    *(uintx4*)&Ks[buf][r0i][s0i * 8] = kreg0;
    *(uintx4*)&Ks[buf][r1i][s0i * 8] = kreg1;
    __syncthreads();                               // barrier A
    // prefetch next K chunk
    if (ch + 1 < 13){
      int c0n = (ch + 1) * 64;
      int t0 = c0n + r0i; if (t0 > 783) t0 = 783;
      int t1 = c0n + r1i; if (t1 > 783) t1 = 783;
      kreg0 = *(const uintx4*)(qkvg + rowBase + (long)t0 * QLD + 512 + s0i * 8);
      kreg1 = *(const uintx4*)(qkvg + rowBase + (long)t1 * QLD + 512 + s0i * 8);
    }
    // V^T fragments for this chunk (latency hides under QK^T+exp)
    int tv0 = K0 + quad * 8;      if (tv0 > 792) tv0 = 792;
    int tv1 = K0 + 32 + quad * 8; if (tv1 > 792) tv1 = 792;
    bf16x8 bv0 = *(const bf16x8*)(vbase + tv0);
    bf16x8 bv1 = *(const bf16x8*)(vbase + tv1);
    // QK^T (S^T layout: lane holds q=l16 / 16+l16, keys K0+w*16+quad*4+{0..3})
    bf16x8 k0 = *(bf16x8*)&Ks[buf][w * 16 + l16][quad * 8];
    bf16x8 k1 = *(bf16x8*)&Ks[buf][w * 16 + l16][32 + quad * 8];
    floatx4 d0 = (floatx4)(0.0f), d1 = (floatx4)(0.0f);
    d0 = __builtin_amdgcn_mfma_f32_16x16x32_bf16(k0, a00, d0, 0, 0, 0);
    d0 = __builtin_amdgcn_mfma_f32_16x16x32_bf16(k1, a01, d0, 0, 0, 0);
    d1 = __builtin_amdgcn_mfma_f32_16x16x32_bf16(k0, a10, d1, 0, 0, 0);
    d1 = __builtin_amdgcn_mfma_f32_16x16x32_bf16(k1, a11, d1, 0, 0, 0);
    int kb = K0 + w * 16 + quad * 4;
    union { bf16_t hh[4]; uintx2 v; } pw0, ps0, pw1, ps1;
#pragma unroll
    for (int r = 0; r < 4; r++){
      int key = kb + r;
      float ex0 = __expf(d0[r] * scale);
      float ex1 = __expf(d1[r] * scale);
      bool valid = key < 784;
      float vw0 = (valid && key >= iq0 - 195 && key <= iq0 + 195) ? ex0 : 0.0f;
      float vs0 = (valid && ((key >= 392) == sv0))                ? ex0 : 0.0f;
      float vw1 = (valid && key >= iq1 - 195 && key <= iq1 + 195) ? ex1 : 0.0f;
      float vs1 = (valid && ((key >= 392) == sv1))                ? ex1 : 0.0f;
      sw0 += vw0; ss0 += vs0; sw1 += vw1; ss1 += vs1;
      pw0.hh[r] = __float2bfloat16(vw0);
      ps0.hh[r] = __float2bfloat16(vs0);
      pw1.hh[r] = __float2bfloat16(vw1);
      ps1.hh[r] = __float2bfloat16(vs1);
    }
    int kloc = w * 16 + quad * 4;
    *(uintx2*)&Wcw[buf][l16][kloc] = pw0.v;
    *(uintx2*)&Wcs[buf][l16][kloc] = ps0.v;
    if (l16 < 12){
      *(uintx2*)&Wcw[buf][16 + l16][kloc] = pw1.v;
      *(uintx2*)&Wcs[buf][16 + l16][kloc] = ps1.v;
    }
    __syncthreads();                               // barrier B
    // PV: wave w owns d = w*16+l16; A = Wc rows (q), B = V^T
#pragma unroll
    for (int ks = 0; ks < 2; ks++){
      bf16x8 bv = ks ? bv1 : bv0;
      bf16x8 aw0 = *(bf16x8*)&Wcw[buf][l16][ks * 32 + quad * 8];
      bf16x8 aw1 = *(bf16x8*)&Wcw[buf][16 + l16][ks * 32 + quad * 8];
      bf16x8 as0 = *(bf16x8*)&Wcs[buf][l16][ks * 32 + quad * 8];
      bf16x8 as1 = *(bf16x8*)&Wcs[buf][16 + l16][ks * 32 + quad * 8];
      ow0 = __builtin_amdgcn_mfma_f32_16x16x32_bf16(aw0, bv, ow0, 0, 0, 0);
      ow1 = __builtin_amdgcn_mfma_f32_16x16x32_bf16(aw1, bv, ow1, 0, 0, 0);
      os0 = __builtin_amdgcn_mfma_f32_16x16x32_bf16(as0, bv, os0, 0, 0, 0);
      os1 = __builtin_amdgcn_mfma_f32_16x16x32_bf16(as1, bv, os1, 0, 0, 0);
    }
  }

  // ---- combine row sums: quads via shfl, waves via 1KB LDS ----
  sw0 += __shfl_xor(sw0, 16, 64); sw0 += __shfl_xor(sw0, 32, 64);
  ss0 += __shfl_xor(ss0, 16, 64); ss0 += __shfl_xor(ss0, 32, 64);
  sw1 += __shfl_xor(sw1, 16, 64); sw1 += __shfl_xor(sw1, 32, 64);
  ss1 += __shfl_xor(ss1, 16, 64); ss1 += __shfl_xor(ss1, 32, 64);
  if (quad == 0){
    red_s[w][0][l16] = sw0; red_s[w][1][l16] = ss0;
    red_s[w][2][l16] = sw1; red_s[w][3][l16] = ss1;
  }
  __syncthreads();
  if (tid < 28){
    int q = tid, t = q >> 4, l = q & 15;
    float sw = 0.f, ss = 0.f;
#pragma unroll
    for (int wv = 0; wv < 4; wv++){ sw += red_s[wv][2 * t][l]; ss += red_s[wv][2 * t + 1][l]; }
    cw_s[q] = g2_s[q] / sw;
    cs_s[q] = g1_s[q] / ss;
  }
  __syncthreads();

  // ---- epilogue: scale branches, add compressed branch, write bf16 ----
  int d = w * 16 + l16;
#pragma unroll
  for (int reg = 0; reg < 4; reg++){
    int q = quad * 4 + reg;
    float o = cw_s[q] * ow0[reg] + cs_s[q] * os0[reg] + outc_s[q][d];
    oattn[((long)(b * SEQ_ + i0 + q)) * DIMC + h * 64 + d] = __float2bfloat16(o);
    int q2 = q + 16;
    if (q2 < 28){
      float o2 = cw_s[q2] * ow1[reg] + cs_s[q2] * os1[reg] + outc_s[q2][d];
      oattn[((long)(b * SEQ_ + i0 + q2)) * DIMC + h * 64 + d] = __float2bfloat16(o2);
    }
  }
}

// ---------------- host launcher ----------------
extern "C" void kernel_launch(void* const* d_in, const int* in_sizes, int n_in,
                              void* d_out, int out_size, void* d_ws, size_t ws_size,
                              hipStream_t stream){
  const float* xin  = (const float*)d_in[0];
  const float* pos  = (const float*)d_in[1];
  const float* angm = (const float*)d_in[2];
  const float* Wq   = (const float*)d_in[3];
  const float* Wk   = (const float*)d_in[4];
  const float* Wv   = (const float*)d_in[5];
  const float* Wo   = (const float*)d_in[6];
  const float* Wg   = (const float*)d_in[7];
  const float* fng  = (const float*)d_in[8];
  const float* fnb  = (const float*)d_in[9];
  const float* fw1  = (const float*)d_in[10];
  const float* fb1  = (const float*)d_in[11];
  const float* fw2  = (const float*)d_in[12];
  const float* fb2  = (const float*)d_in[13];

  // workspace layout: ~70.7 MB total (BUFb/H1b share one region — disjoint live ranges)
  char* cw = (char*)d_ws;
  float* X = (float*)cw;             cw += (long)NTOK * 512 * 4;     // 12.85 MB
  bf16_t* XRb = (bf16_t*)cw;         cw += (long)NTOK * 512 * 2;     //  6.42 MB
  bf16_t* OAb = (bf16_t*)cw;         cw += (long)NTOK * 512 * 2;     //  6.42 MB
  bf16_t* SH  = (bf16_t*)cw;         cw += (long)NTOK * FF_ * 2;     // 25.69 MB (BUFb/H1b)
  float* CK = (float*)cw;            cw += (long)B_ * NC_ * DIMC * 4;
  float* CV = (float*)cw;            cw += (long)B_ * NC_ * DIMC * 4;
  bf16_t* Wqkvgb = (bf16_t*)cw;      cw += (long)2 * QLD * 512 * 2;  //  3.19 MB
  bf16_t* WOb    = (bf16_t*)cw;      cw += (long)2 * 512 * 512 * 2;  //  1.05 MB
  bf16_t* FW1b   = (bf16_t*)cw;      cw += (long)2 * FF_ * 512 * 2;  //  4.19 MB
  bf16_t* FW2b   = (bf16_t*)cw;      cw += (long)2 * 512 * FF_ * 2;  //  4.19 MB
  bf16_t* VTb    = (bf16_t*)cw;      cw += (long)B_ * 512 * 800 * 2; //  6.55 MB
  bf16_t* BUFb = SH;   // [NTOK, QLD]  (QKVG output; dies after k_attn)
  bf16_t* H1b  = SH;   // [NTOK, FF_]  (FF1 output; born after k_ln)

  // per-call weight conversion (deterministic, same work every call)
  k_wconv1<<<2 * 49 * 16, 256, 0, stream>>>(Wq, Wk, Wv, Wg, Wqkvgb);
  k_wconv2<<<2 * 16 * 16, 256, 0, stream>>>(Wo, WOb);
  k_cast<<<(2 * FF_ * 512) / 256, 256, 0, stream>>>(fw1, FW1b);
  k_cast<<<(2 * 512 * FF_) / 256, 256, 0, stream>>>(fw2, FW2b);

  // zero VT once: tokens 784..799 stay zero; cols 0..783 rewritten each layer
  k_zero<<<1600, 256, 0, stream>>>((uintx4*)VTb);   // 6,553,600 B

  k_init<<<8 * 25 * 16, 256, 0, stream>>>(xin, pos, X);

  for (int l = 0; l < 2; l++){
    k_rms<<<NTOK, 256, 0, stream>>>(X, angm + (long)l * DIMC, XRb);

    // fused QKV+G GEMM: [6272,512] x [1560,512]^T -> BUFb [6272,1560] bf16 (+ VT)
    k_mgemm<1, 0, 128, 32><<<13 * 104, 256, 0, stream>>>(
        XRb, Wqkvgb + (long)l * QLD * 512, nullptr, BUFb, nullptr, nullptr,
        NTOK, QLD, 512, QLD, 0, VTb);

    k_cpool<<<B_ * NC_, 512, 0, stream>>>(BUFb, CK, CV);

    k_attn<<<8 * 8 * 28, 256, 0, stream>>>(BUFb, CK, CV, VTb, OAb);

    // Wo GEMM: f32 out + residual into X (TN=64, BK=64)
    k_mgemm<0, 0, 64, 64><<<8 * 104, 256, 0, stream>>>(
        OAb, WOb + (long)l * 512 * 512, X, nullptr, nullptr, X,
        NTOK, 512, 512, 512, 0, nullptr);

    k_ln<<<NTOK, 256, 0, stream>>>(X, fng + (long)l * DIMC, fnb + (long)l * DIMC, XRb);

    // FF1 + GELU, bf16 out into H1b (TN=128)
    k_mgemm<1, 1, 128, 32><<<16 * 104, 256, 0, stream>>>(
        XRb, FW1b + (long)l * FF_ * 512, nullptr, H1b, fb1 + (long)l * FF_, nullptr,
        NTOK, FF_, 512, FF_, 0, nullptr);
    // FF2, f32 out + residual into X (TN=64, BK=64)
    k_mgemm<0, 0, 64, 64><<<8 * 104, 256, 0, stream>>>(
        H1b, FW2b + (long)l * 512 * FF_, X, nullptr, fb2 + (long)l * DIMC, X,
        NTOK, 512, FF_, 512, 0, nullptr);
  }

  k_final<<<8 * 25 * 16, 256, 0, stream>>>(X, (float*)d_out);
}